// Round 1
// baseline (227.343 us; speedup 1.0000x reference)
//
#include <hip/hip_runtime.h>
#include <math.h>

#define Cn 192
#define Bn 8
#define Tn 4096
#define HW 64

// ---------------------------------------------------------------------------
// Kernel 1: omni_shift — fused depthwise 5x5 (dw5) + 3x3 (dw3) + 1x1 (dw1) + identity
// One block per (b,c) plane of 64x64. Effective 25-tap kernel built once in LDS.
// ---------------------------------------------------------------------------
__global__ __launch_bounds__(256) void omni_kernel(const float* __restrict__ x,
                                                   const float* __restrict__ alpha,
                                                   const float* __restrict__ dw1,
                                                   const float* __restrict__ dw3,
                                                   const float* __restrict__ dw5,
                                                   float* __restrict__ xs) {
    const int plane = blockIdx.x;          // b*C + c
    const int c = plane % Cn;
    const float* xin = x + (size_t)plane * Tn;
    float* xout = xs + (size_t)plane * Tn;

    __shared__ float tile[68 * 68];
    __shared__ float wk[25];

    const int tid = threadIdx.x;
    if (tid == 0) {
        const float a0 = alpha[0], a1 = alpha[1], a2 = alpha[2], a3 = alpha[3];
        #pragma unroll
        for (int j = 0; j < 25; ++j) wk[j] = a3 * dw5[c * 25 + j];
        #pragma unroll
        for (int dy = 0; dy < 3; ++dy)
            #pragma unroll
            for (int dx = 0; dx < 3; ++dx)
                wk[(dy + 1) * 5 + (dx + 1)] += a2 * dw3[c * 9 + dy * 3 + dx];
        wk[12] += a1 * dw1[c] + a0;
    }
    // load 68x68 halo tile (zero padded)
    for (int i = tid; i < 68 * 68; i += 256) {
        int r = i / 68, cc = i - r * 68;
        int gy = r - 2, gx = cc - 2;
        float v = 0.f;
        if (gy >= 0 && gy < HW && gx >= 0 && gx < HW) v = xin[gy * HW + gx];
        tile[i] = v;
    }
    __syncthreads();

    for (int p = tid; p < Tn; p += 256) {
        int py = p >> 6, px = p & 63;
        float acc = 0.f;
        #pragma unroll
        for (int dy = 0; dy < 5; ++dy) {
            #pragma unroll
            for (int dx = 0; dx < 5; ++dx) {
                acc = fmaf(tile[(py + dy) * 68 + (px + dx)], wk[dy * 5 + dx], acc);
            }
        }
        xout[p] = acc;
    }
}

// ---------------------------------------------------------------------------
// Kernel 2: f32 GEMM  C[b][m][t] = sum_c A[m][c] * B[b][c][t]
// A: 192x192 row-major (shared across batch); B: per-batch 192x4096; C: per-batch 192x4096
// 64x64 tile per block, 256 threads, 4x4 micro-tile, K staged in LDS by 32.
// ---------------------------------------------------------------------------
__global__ __launch_bounds__(256) void gemm192_kernel(const float* __restrict__ A,
                                                      const float* __restrict__ Bg,
                                                      float* __restrict__ Cg) {
    const int K = Cn;                 // 192
    const int N = Tn;                 // 4096
    const int bt = blockIdx.x;        // N tile
    const int mt = blockIdx.y;        // M tile (M=192 -> 3 tiles)
    const int bz = blockIdx.z;        // batch

    const float* B = Bg + (size_t)bz * K * N;
    float* C = Cg + (size_t)bz * Cn * N;

    __shared__ float As[32][68];      // transposed A tile: [kk][row], padded (row stride 272B, 16B-aligned)
    __shared__ float Bs[32][64];      // [kk][col]

    const int tid = threadIdx.x;
    const int tx = tid & 15;
    const int ty = tid >> 4;
    const int row0 = mt * 64;
    const int col0 = bt * 64;

    float acc[4][4];
    #pragma unroll
    for (int i = 0; i < 4; ++i)
        #pragma unroll
        for (int j = 0; j < 4; ++j) acc[i][j] = 0.f;

    for (int k0 = 0; k0 < K; k0 += 32) {
        // stage A tile 64x32 (transposed into LDS)
        #pragma unroll
        for (int i = tid; i < 64 * 32; i += 256) {
            int r = i >> 5, cc = i & 31;
            As[cc][r] = A[(size_t)(row0 + r) * K + (k0 + cc)];
        }
        // stage B tile 32x64
        #pragma unroll
        for (int i = tid; i < 32 * 64; i += 256) {
            int r = i >> 6, cc = i & 63;
            Bs[r][cc] = B[(size_t)(k0 + r) * N + col0 + cc];
        }
        __syncthreads();

        #pragma unroll 8
        for (int kk = 0; kk < 32; ++kk) {
            const float4 av = *(const float4*)&As[kk][ty * 4];
            const float4 bv = *(const float4*)&Bs[kk][tx * 4];
            float a4[4] = {av.x, av.y, av.z, av.w};
            float b4[4] = {bv.x, bv.y, bv.z, bv.w};
            #pragma unroll
            for (int i = 0; i < 4; ++i)
                #pragma unroll
                for (int j = 0; j < 4; ++j)
                    acc[i][j] = fmaf(a4[i], b4[j], acc[i][j]);
        }
        __syncthreads();
    }

    #pragma unroll
    for (int i = 0; i < 4; ++i) {
        float4 o = make_float4(acc[i][0], acc[i][1], acc[i][2], acc[i][3]);
        *(float4*)&C[(size_t)(row0 + ty * 4 + i) * N + col0 + tx * 4] = o;
    }
}

// ---------------------------------------------------------------------------
// Kernel 3: bidirectional WKV + sigmoid(receptance) fused.
// One block per (b,d) row of length T=4096. 256 threads x 16-elem chunks.
// Constant-coefficient linear recurrence parallelized via Hillis-Steele scan.
// All sums scaled by exp(-m), m = row max of k (ratio-invariant).
// ---------------------------------------------------------------------------
__global__ __launch_bounds__(256) void wkv_kernel(const float* __restrict__ kg,
                                                  const float* __restrict__ vg,
                                                  const float* __restrict__ srlg,
                                                  const float* __restrict__ decay,
                                                  const float* __restrict__ boost,
                                                  float* __restrict__ yp) {
    const int row = blockIdx.x;       // b*C + d
    const int d = row % Cn;
    const float* kr = kg + (size_t)row * Tn;
    const float* vr = vg + (size_t)row * Tn;
    const float* sr = srlg + (size_t)row * Tn;
    float* yr = yp + (size_t)row * Tn;

    const int tid = threadIdx.x;
    const int t0 = tid * 16;

    float kk[16], vv[16];
    #pragma unroll
    for (int j = 0; j < 16; j += 4) {
        *(float4*)&kk[j] = *(const float4*)&kr[t0 + j];
        *(float4*)&vv[j] = *(const float4*)&vr[t0 + j];
    }

    // row max of k
    __shared__ float red[256];
    float lm = kk[0];
    #pragma unroll
    for (int j = 1; j < 16; ++j) lm = fmaxf(lm, kk[j]);
    red[tid] = lm;
    __syncthreads();
    for (int s = 128; s > 0; s >>= 1) {
        if (tid < s) red[tid] = fmaxf(red[tid], red[tid + s]);
        __syncthreads();
    }
    const float m = red[0];
    __syncthreads();

    const float w = decay[d] * (1.0f / (float)Tn);
    const float u = boost[d] * (1.0f / (float)Tn);
    const float lam = expf(-w);
    const float lam16 = expf(-16.0f * w);

    float a[16];
    #pragma unroll
    for (int j = 0; j < 16; ++j) a[j] = expf(kk[j] - m);

    // local chunk summaries
    float SN = 0.f, SD = 0.f;          // forward: sum a_j v_j lam^{15-j}
    #pragma unroll
    for (int j = 0; j < 16; ++j) {
        SN = fmaf(lam, SN, a[j] * vv[j]);
        SD = fmaf(lam, SD, a[j]);
    }
    float BN = 0.f, BD = 0.f;          // backward: sum a_j v_j lam^{j}
    #pragma unroll
    for (int j = 15; j >= 0; --j) {
        BN = fmaf(lam, BN, a[j] * vv[j]);
        BD = fmaf(lam, BD, a[j]);
    }

    __shared__ float sN[2][256], sD[2][256];

    // ---- forward cross-chunk inclusive decayed scan ----
    sN[0][tid] = SN; sD[0][tid] = SD;
    __syncthreads();
    int src = 0;
    float f = lam16;
    for (int o = 1; o < 256; o <<= 1) {
        float nN = sN[src][tid], nD = sD[src][tid];
        if (tid >= o) {
            nN = fmaf(f, sN[src][tid - o], nN);
            nD = fmaf(f, sD[src][tid - o], nD);
        }
        sN[src ^ 1][tid] = nN; sD[src ^ 1][tid] = nD;
        __syncthreads();
        src ^= 1;
        f = f * f;
    }
    const float CfN = (tid > 0) ? sN[src][tid - 1] : 0.f;
    const float CfD = (tid > 0) ? sD[src][tid - 1] : 0.f;
    __syncthreads();

    // ---- backward cross-chunk scan (from the right) ----
    sN[0][tid] = BN; sD[0][tid] = BD;
    __syncthreads();
    src = 0;
    f = lam16;
    for (int o = 1; o < 256; o <<= 1) {
        float nN = sN[src][tid], nD = sD[src][tid];
        if (tid + o < 256) {
            nN = fmaf(f, sN[src][tid + o], nN);
            nD = fmaf(f, sD[src][tid + o], nD);
        }
        sN[src ^ 1][tid] = nN; sD[src ^ 1][tid] = nD;
        __syncthreads();
        src ^= 1;
        f = f * f;
    }
    const float CbN = (tid < 255) ? sN[src][tid + 1] : 0.f;
    const float CbD = (tid < 255) ? sD[src][tid + 1] : 0.f;

    // ---- within-chunk forward sweep (exclusive states) ----
    float fN[16], fD[16];
    float cN = CfN, cD = CfD;
    #pragma unroll
    for (int j = 0; j < 16; ++j) {
        fN[j] = cN; fD[j] = cD;
        cN = fmaf(lam, cN, a[j] * vv[j]);
        cD = fmaf(lam, cD, a[j]);
    }

    // receptance logits
    float sl[16];
    #pragma unroll
    for (int j = 0; j < 16; j += 4) {
        *(float4*)&sl[j] = *(const float4*)&sr[t0 + j];
    }

    // ---- within-chunk backward sweep + combine + sigmoid ----
    float outv[16];
    float bN = CbN, bD = CbD;
    #pragma unroll
    for (int j = 15; j >= 0; --j) {
        const float es = expf(u + kk[j] - m);
        const float num = fN[j] + bN + es * vv[j];
        const float den = fD[j] + bD + es;
        const float y = num / den;
        const float sig = 1.0f / (1.0f + expf(-sl[j]));
        outv[j] = sig * y;
        bN = fmaf(lam, bN, a[j] * vv[j]);
        bD = fmaf(lam, bD, a[j]);
    }

    #pragma unroll
    for (int j = 0; j < 16; j += 4) {
        *(float4*)&yr[t0 + j] = *(const float4*)&outv[j];
    }
}

// ---------------------------------------------------------------------------
extern "C" void kernel_launch(void* const* d_in, const int* in_sizes, int n_in,
                              void* d_out, int out_size, void* d_ws, size_t ws_size,
                              hipStream_t stream) {
    const float* x        = (const float*)d_in[0];
    const float* w_key    = (const float*)d_in[1];
    const float* w_value  = (const float*)d_in[2];
    const float* w_recept = (const float*)d_in[3];
    const float* w_out    = (const float*)d_in[4];
    const float* decay    = (const float*)d_in[5];
    const float* boost    = (const float*)d_in[6];
    const float* alpha    = (const float*)d_in[7];
    const float* dw1      = (const float*)d_in[8];
    const float* dw3      = (const float*)d_in[9];
    const float* dw5      = (const float*)d_in[10];

    const size_t S = (size_t)Bn * Cn * Tn;   // elements per buffer
    float* xs  = (float*)d_ws;
    float* kb  = xs + S;
    float* vb  = kb + S;
    float* srl = vb + S;
    float* ypb = xs;                          // reuse xs after projections
    float* out = (float*)d_out;

    omni_kernel<<<dim3(Bn * Cn), 256, 0, stream>>>(x, alpha, dw1, dw3, dw5, xs);

    gemm192_kernel<<<dim3(Tn / 64, 3, Bn), 256, 0, stream>>>(w_key, xs, kb);
    gemm192_kernel<<<dim3(Tn / 64, 3, Bn), 256, 0, stream>>>(w_value, xs, vb);
    gemm192_kernel<<<dim3(Tn / 64, 3, Bn), 256, 0, stream>>>(w_recept, xs, srl);

    wkv_kernel<<<dim3(Bn * Cn), 256, 0, stream>>>(kb, vb, srl, decay, boost, ypb);

    gemm192_kernel<<<dim3(Tn / 64, 3, Bn), 256, 0, stream>>>(w_out, ypb, out);
}

// Round 2
// 201.803 us; speedup vs baseline: 1.1266x; 1.1266x over previous
//
#include <hip/hip_runtime.h>
#include <math.h>

#define Cn 192
#define Bn 8
#define Tn 4096
#define HW 64

// ---------------------------------------------------------------------------
// Kernel 1: omni_shift — fused depthwise 5x5 (dw5) + 3x3 (dw3) + 1x1 (dw1) + identity
// One block per (b,c) plane of 64x64. Effective 25-tap kernel built once in LDS.
// ---------------------------------------------------------------------------
__global__ __launch_bounds__(256) void omni_kernel(const float* __restrict__ x,
                                                   const float* __restrict__ alpha,
                                                   const float* __restrict__ dw1,
                                                   const float* __restrict__ dw3,
                                                   const float* __restrict__ dw5,
                                                   float* __restrict__ xs) {
    const int plane = blockIdx.x;          // b*C + c
    const int c = plane % Cn;
    const float* xin = x + (size_t)plane * Tn;
    float* xout = xs + (size_t)plane * Tn;

    __shared__ float tile[68 * 68];
    __shared__ float wk[25];

    const int tid = threadIdx.x;
    if (tid == 0) {
        const float a0 = alpha[0], a1 = alpha[1], a2 = alpha[2], a3 = alpha[3];
        #pragma unroll
        for (int j = 0; j < 25; ++j) wk[j] = a3 * dw5[c * 25 + j];
        #pragma unroll
        for (int dy = 0; dy < 3; ++dy)
            #pragma unroll
            for (int dx = 0; dx < 3; ++dx)
                wk[(dy + 1) * 5 + (dx + 1)] += a2 * dw3[c * 9 + dy * 3 + dx];
        wk[12] += a1 * dw1[c] + a0;
    }
    // load 68x68 halo tile (zero padded)
    for (int i = tid; i < 68 * 68; i += 256) {
        int r = i / 68, cc = i - r * 68;
        int gy = r - 2, gx = cc - 2;
        float v = 0.f;
        if (gy >= 0 && gy < HW && gx >= 0 && gx < HW) v = xin[gy * HW + gx];
        tile[i] = v;
    }
    __syncthreads();

    for (int p = tid; p < Tn; p += 256) {
        int py = p >> 6, px = p & 63;
        float acc = 0.f;
        #pragma unroll
        for (int dy = 0; dy < 5; ++dy) {
            #pragma unroll
            for (int dx = 0; dx < 5; ++dx) {
                acc = fmaf(tile[(py + dy) * 68 + (px + dx)], wk[dy * 5 + dx], acc);
            }
        }
        xout[p] = acc;
    }
}

// ---------------------------------------------------------------------------
// Kernel 2: fused k/v/sr projection GEMM.
// C_x[b][m][t] = sum_c W_x[m][c] * xs[b][c][t]  for x in {key, value, recept}
// 64x64 tile, 256 threads, 4x4 micro-tile per output, 3 accumulator sets.
// One shared B tile per k-step serves 3 weight tiles -> FMA-bound (48 FMA per
// 4 ds_read_b128) and xs fetched from HBM once instead of 3x.
// ---------------------------------------------------------------------------
__global__ __launch_bounds__(256) void fused_proj_kernel(const float* __restrict__ Wk,
                                                         const float* __restrict__ Wv,
                                                         const float* __restrict__ Wr,
                                                         const float* __restrict__ Bg,
                                                         float* __restrict__ kout,
                                                         float* __restrict__ vout,
                                                         float* __restrict__ rout) {
    const int K = Cn;                 // 192
    const int N = Tn;                 // 4096
    const int bt = blockIdx.x;        // N tile (64 tiles)
    const int mt = blockIdx.y;        // M tile (3)
    const int bz = blockIdx.z;        // batch (8)

    const float* B = Bg + (size_t)bz * K * N;

    __shared__ float As[3][32][68];   // [mat][kk][row], padded (272B stride, 16B aligned)
    __shared__ float Bs[32][64];      // [kk][col]

    const int tid = threadIdx.x;
    const int tx = tid & 15;
    const int ty = tid >> 4;
    const int row0 = mt * 64;
    const int col0 = bt * 64;

    float ak4[4][4], av4[4][4], ar4[4][4];
    #pragma unroll
    for (int i = 0; i < 4; ++i)
        #pragma unroll
        for (int j = 0; j < 4; ++j) { ak4[i][j] = 0.f; av4[i][j] = 0.f; ar4[i][j] = 0.f; }

    for (int k0 = 0; k0 < K; k0 += 32) {
        // stage the 3 A tiles (64x32 each, transposed into LDS)
        #pragma unroll
        for (int i = tid; i < 64 * 32; i += 256) {
            int r = i >> 5, cc = i & 31;
            size_t gi = (size_t)(row0 + r) * K + (k0 + cc);
            As[0][cc][r] = Wk[gi];
            As[1][cc][r] = Wv[gi];
            As[2][cc][r] = Wr[gi];
        }
        // stage B tile 32x64
        #pragma unroll
        for (int i = tid; i < 32 * 64; i += 256) {
            int r = i >> 6, cc = i & 63;
            Bs[r][cc] = B[(size_t)(k0 + r) * N + col0 + cc];
        }
        __syncthreads();

        #pragma unroll 8
        for (int kk = 0; kk < 32; ++kk) {
            const float4 wkv_ = *(const float4*)&As[0][kk][ty * 4];
            const float4 wvv_ = *(const float4*)&As[1][kk][ty * 4];
            const float4 wrv_ = *(const float4*)&As[2][kk][ty * 4];
            const float4 bv   = *(const float4*)&Bs[kk][tx * 4];
            const float b4[4] = {bv.x, bv.y, bv.z, bv.w};
            const float k4[4] = {wkv_.x, wkv_.y, wkv_.z, wkv_.w};
            const float v4[4] = {wvv_.x, wvv_.y, wvv_.z, wvv_.w};
            const float r4[4] = {wrv_.x, wrv_.y, wrv_.z, wrv_.w};
            #pragma unroll
            for (int i = 0; i < 4; ++i)
                #pragma unroll
                for (int j = 0; j < 4; ++j) {
                    ak4[i][j] = fmaf(k4[i], b4[j], ak4[i][j]);
                    av4[i][j] = fmaf(v4[i], b4[j], av4[i][j]);
                    ar4[i][j] = fmaf(r4[i], b4[j], ar4[i][j]);
                }
        }
        __syncthreads();
    }

    const size_t obase = (size_t)bz * Cn * N;
    #pragma unroll
    for (int i = 0; i < 4; ++i) {
        const size_t ro = obase + (size_t)(row0 + ty * 4 + i) * N + col0 + tx * 4;
        *(float4*)&kout[ro] = make_float4(ak4[i][0], ak4[i][1], ak4[i][2], ak4[i][3]);
        *(float4*)&vout[ro] = make_float4(av4[i][0], av4[i][1], av4[i][2], av4[i][3]);
        *(float4*)&rout[ro] = make_float4(ar4[i][0], ar4[i][1], ar4[i][2], ar4[i][3]);
    }
}

// ---------------------------------------------------------------------------
// Kernel 3: output projection GEMM. 64x128 tile, 4x8 micro-tile (two 64-wide
// column halves -> B reads stay 2-way broadcast, conflict-free).
// ---------------------------------------------------------------------------
__global__ __launch_bounds__(256) void gemm_out_kernel(const float* __restrict__ A,
                                                       const float* __restrict__ Bg,
                                                       float* __restrict__ Cg) {
    const int K = Cn;
    const int N = Tn;
    const int bt = blockIdx.x;        // N tile (32 tiles of 128)
    const int mt = blockIdx.y;        // M tile (3)
    const int bz = blockIdx.z;        // batch

    const float* B = Bg + (size_t)bz * K * N;
    float* C = Cg + (size_t)bz * Cn * N;

    __shared__ float As[32][68];
    __shared__ float Bs[32][128];

    const int tid = threadIdx.x;
    const int tx = tid & 15;
    const int ty = tid >> 4;
    const int row0 = mt * 64;
    const int col0 = bt * 128;

    float acc[4][8];
    #pragma unroll
    for (int i = 0; i < 4; ++i)
        #pragma unroll
        for (int j = 0; j < 8; ++j) acc[i][j] = 0.f;

    for (int k0 = 0; k0 < K; k0 += 32) {
        #pragma unroll
        for (int i = tid; i < 64 * 32; i += 256) {
            int r = i >> 5, cc = i & 31;
            As[cc][r] = A[(size_t)(row0 + r) * K + (k0 + cc)];
        }
        #pragma unroll
        for (int i = tid; i < 32 * 128; i += 256) {
            int r = i >> 7, cc = i & 127;
            Bs[r][cc] = B[(size_t)(k0 + r) * N + col0 + cc];
        }
        __syncthreads();

        #pragma unroll 8
        for (int kk = 0; kk < 32; ++kk) {
            const float4 avv = *(const float4*)&As[kk][ty * 4];
            const float4 b0v = *(const float4*)&Bs[kk][tx * 4];
            const float4 b1v = *(const float4*)&Bs[kk][64 + tx * 4];
            const float a4[4] = {avv.x, avv.y, avv.z, avv.w};
            const float b8[8] = {b0v.x, b0v.y, b0v.z, b0v.w, b1v.x, b1v.y, b1v.z, b1v.w};
            #pragma unroll
            for (int i = 0; i < 4; ++i)
                #pragma unroll
                for (int j = 0; j < 8; ++j)
                    acc[i][j] = fmaf(a4[i], b8[j], acc[i][j]);
        }
        __syncthreads();
    }

    #pragma unroll
    for (int i = 0; i < 4; ++i) {
        const size_t ro = (size_t)(row0 + ty * 4 + i) * N + col0;
        *(float4*)&C[ro + tx * 4]      = make_float4(acc[i][0], acc[i][1], acc[i][2], acc[i][3]);
        *(float4*)&C[ro + 64 + tx * 4] = make_float4(acc[i][4], acc[i][5], acc[i][6], acc[i][7]);
    }
}

// ---------------------------------------------------------------------------
// Kernel 4: bidirectional WKV + sigmoid(receptance) fused.
// One block per (b,d) row of length T=4096. 256 threads x 16-elem chunks.
// Constant-coefficient linear recurrence parallelized via Hillis-Steele scan.
// All sums scaled by exp(-m), m = row max of k (ratio-invariant).
// ---------------------------------------------------------------------------
__global__ __launch_bounds__(256) void wkv_kernel(const float* __restrict__ kg,
                                                  const float* __restrict__ vg,
                                                  const float* __restrict__ srlg,
                                                  const float* __restrict__ decay,
                                                  const float* __restrict__ boost,
                                                  float* __restrict__ yp) {
    const int row = blockIdx.x;       // b*C + d
    const int d = row % Cn;
    const float* kr = kg + (size_t)row * Tn;
    const float* vr = vg + (size_t)row * Tn;
    const float* sr = srlg + (size_t)row * Tn;
    float* yr = yp + (size_t)row * Tn;

    const int tid = threadIdx.x;
    const int t0 = tid * 16;

    float kk[16], vv[16];
    #pragma unroll
    for (int j = 0; j < 16; j += 4) {
        *(float4*)&kk[j] = *(const float4*)&kr[t0 + j];
        *(float4*)&vv[j] = *(const float4*)&vr[t0 + j];
    }

    // row max of k
    __shared__ float red[256];
    float lm = kk[0];
    #pragma unroll
    for (int j = 1; j < 16; ++j) lm = fmaxf(lm, kk[j]);
    red[tid] = lm;
    __syncthreads();
    for (int s = 128; s > 0; s >>= 1) {
        if (tid < s) red[tid] = fmaxf(red[tid], red[tid + s]);
        __syncthreads();
    }
    const float m = red[0];
    __syncthreads();

    const float w = decay[d] * (1.0f / (float)Tn);
    const float u = boost[d] * (1.0f / (float)Tn);
    const float lam = expf(-w);
    const float lam16 = expf(-16.0f * w);

    float a[16];
    #pragma unroll
    for (int j = 0; j < 16; ++j) a[j] = expf(kk[j] - m);

    // local chunk summaries
    float SN = 0.f, SD = 0.f;          // forward: sum a_j v_j lam^{15-j}
    #pragma unroll
    for (int j = 0; j < 16; ++j) {
        SN = fmaf(lam, SN, a[j] * vv[j]);
        SD = fmaf(lam, SD, a[j]);
    }
    float BN = 0.f, BD = 0.f;          // backward: sum a_j v_j lam^{j}
    #pragma unroll
    for (int j = 15; j >= 0; --j) {
        BN = fmaf(lam, BN, a[j] * vv[j]);
        BD = fmaf(lam, BD, a[j]);
    }

    __shared__ float sN[2][256], sD[2][256];

    // ---- forward cross-chunk inclusive decayed scan ----
    sN[0][tid] = SN; sD[0][tid] = SD;
    __syncthreads();
    int src = 0;
    float f = lam16;
    for (int o = 1; o < 256; o <<= 1) {
        float nN = sN[src][tid], nD = sD[src][tid];
        if (tid >= o) {
            nN = fmaf(f, sN[src][tid - o], nN);
            nD = fmaf(f, sD[src][tid - o], nD);
        }
        sN[src ^ 1][tid] = nN; sD[src ^ 1][tid] = nD;
        __syncthreads();
        src ^= 1;
        f = f * f;
    }
    const float CfN = (tid > 0) ? sN[src][tid - 1] : 0.f;
    const float CfD = (tid > 0) ? sD[src][tid - 1] : 0.f;
    __syncthreads();

    // ---- backward cross-chunk scan (from the right) ----
    sN[0][tid] = BN; sD[0][tid] = BD;
    __syncthreads();
    src = 0;
    f = lam16;
    for (int o = 1; o < 256; o <<= 1) {
        float nN = sN[src][tid], nD = sD[src][tid];
        if (tid + o < 256) {
            nN = fmaf(f, sN[src][tid + o], nN);
            nD = fmaf(f, sD[src][tid + o], nD);
        }
        sN[src ^ 1][tid] = nN; sD[src ^ 1][tid] = nD;
        __syncthreads();
        src ^= 1;
        f = f * f;
    }
    const float CbN = (tid < 255) ? sN[src][tid + 1] : 0.f;
    const float CbD = (tid < 255) ? sD[src][tid + 1] : 0.f;

    // ---- within-chunk forward sweep (exclusive states) ----
    float fN[16], fD[16];
    float cN = CfN, cD = CfD;
    #pragma unroll
    for (int j = 0; j < 16; ++j) {
        fN[j] = cN; fD[j] = cD;
        cN = fmaf(lam, cN, a[j] * vv[j]);
        cD = fmaf(lam, cD, a[j]);
    }

    // receptance logits
    float sl[16];
    #pragma unroll
    for (int j = 0; j < 16; j += 4) {
        *(float4*)&sl[j] = *(const float4*)&sr[t0 + j];
    }

    // ---- within-chunk backward sweep + combine + sigmoid ----
    float outv[16];
    float bN = CbN, bD = CbD;
    #pragma unroll
    for (int j = 15; j >= 0; --j) {
        const float es = expf(u + kk[j] - m);
        const float num = fN[j] + bN + es * vv[j];
        const float den = fD[j] + bD + es;
        const float y = num / den;
        const float sig = 1.0f / (1.0f + expf(-sl[j]));
        outv[j] = sig * y;
        bN = fmaf(lam, bN, a[j] * vv[j]);
        bD = fmaf(lam, bD, a[j]);
    }

    #pragma unroll
    for (int j = 0; j < 16; j += 4) {
        *(float4*)&yr[t0 + j] = *(const float4*)&outv[j];
    }
}

// ---------------------------------------------------------------------------
extern "C" void kernel_launch(void* const* d_in, const int* in_sizes, int n_in,
                              void* d_out, int out_size, void* d_ws, size_t ws_size,
                              hipStream_t stream) {
    const float* x        = (const float*)d_in[0];
    const float* w_key    = (const float*)d_in[1];
    const float* w_value  = (const float*)d_in[2];
    const float* w_recept = (const float*)d_in[3];
    const float* w_out    = (const float*)d_in[4];
    const float* decay    = (const float*)d_in[5];
    const float* boost    = (const float*)d_in[6];
    const float* alpha    = (const float*)d_in[7];
    const float* dw1      = (const float*)d_in[8];
    const float* dw3      = (const float*)d_in[9];
    const float* dw5      = (const float*)d_in[10];

    const size_t S = (size_t)Bn * Cn * Tn;   // elements per buffer
    float* xs  = (float*)d_ws;
    float* kb  = xs + S;
    float* vb  = kb + S;
    float* srl = vb + S;
    float* ypb = xs;                          // reuse xs after projections
    float* out = (float*)d_out;

    omni_kernel<<<dim3(Bn * Cn), 256, 0, stream>>>(x, alpha, dw1, dw3, dw5, xs);

    fused_proj_kernel<<<dim3(Tn / 64, 3, Bn), 256, 0, stream>>>(w_key, w_value, w_recept,
                                                                xs, kb, vb, srl);

    wkv_kernel<<<dim3(Bn * Cn), 256, 0, stream>>>(kb, vb, srl, decay, boost, ypb);

    gemm_out_kernel<<<dim3(Tn / 128, 3, Bn), 256, 0, stream>>>(w_out, ypb, out);
}

// Round 3
// 161.125 us; speedup vs baseline: 1.4110x; 1.2525x over previous
//
#include <hip/hip_runtime.h>
#include <math.h>

#define Cn 192
#define Bn 8
#define Tn 4096
#define HW 64

typedef __attribute__((ext_vector_type(8))) __bf16 bf16x8;
typedef __attribute__((ext_vector_type(16))) float f32x16;

__device__ __forceinline__ void split_bf16(float x, unsigned short &h, unsigned short &l) {
    unsigned int u = __float_as_uint(x);
    unsigned int uh = (u + 0x7FFFu + ((u >> 16) & 1u)) & 0xFFFF0000u;
    h = (unsigned short)(uh >> 16);
    float r = x - __uint_as_float(uh);
    unsigned int ur = __float_as_uint(r);
    l = (unsigned short)((ur + 0x7FFFu + ((ur >> 16) & 1u)) >> 16);
}

// ---------------------------------------------------------------------------
// Kernel 0: split the 4 weight matrices into bf16 hi/lo parts.
// ---------------------------------------------------------------------------
__global__ __launch_bounds__(256) void wsplit_kernel(const float* __restrict__ Wk,
                                                     const float* __restrict__ Wv,
                                                     const float* __restrict__ Wr,
                                                     const float* __restrict__ Wo,
                                                     unsigned short* __restrict__ wh,
                                                     unsigned short* __restrict__ wl) {
    const int idx = blockIdx.x * 256 + threadIdx.x;      // 0..36863
    const int mat = blockIdx.y;
    const float* src = (mat == 0) ? Wk : (mat == 1) ? Wv : (mat == 2) ? Wr : Wo;
    unsigned short h, l;
    split_bf16(src[idx], h, l);
    wh[(size_t)mat * 36864 + idx] = h;
    wl[(size_t)mat * 36864 + idx] = l;
}

// ---------------------------------------------------------------------------
// Kernel 1: omni_shift (fused 25-tap depthwise conv) -> split bf16 hi/lo out.
// ---------------------------------------------------------------------------
__global__ __launch_bounds__(256) void omni_kernel(const float* __restrict__ x,
                                                   const float* __restrict__ alpha,
                                                   const float* __restrict__ dw1,
                                                   const float* __restrict__ dw3,
                                                   const float* __restrict__ dw5,
                                                   unsigned short* __restrict__ xhi,
                                                   unsigned short* __restrict__ xlo) {
    const int plane = blockIdx.x;          // b*C + c
    const int c = plane % Cn;
    const float* xin = x + (size_t)plane * Tn;
    unsigned short* oh = xhi + (size_t)plane * Tn;
    unsigned short* ol = xlo + (size_t)plane * Tn;

    __shared__ float tile[68 * 68];
    __shared__ float wk[25];

    const int tid = threadIdx.x;
    if (tid == 0) {
        const float a0 = alpha[0], a1 = alpha[1], a2 = alpha[2], a3 = alpha[3];
        #pragma unroll
        for (int j = 0; j < 25; ++j) wk[j] = a3 * dw5[c * 25 + j];
        #pragma unroll
        for (int dy = 0; dy < 3; ++dy)
            #pragma unroll
            for (int dx = 0; dx < 3; ++dx)
                wk[(dy + 1) * 5 + (dx + 1)] += a2 * dw3[c * 9 + dy * 3 + dx];
        wk[12] += a1 * dw1[c] + a0;
    }
    for (int i = tid; i < 68 * 68; i += 256) {
        int r = i / 68, cc = i - r * 68;
        int gy = r - 2, gx = cc - 2;
        float v = 0.f;
        if (gy >= 0 && gy < HW && gx >= 0 && gx < HW) v = xin[gy * HW + gx];
        tile[i] = v;
    }
    __syncthreads();

    for (int p = tid; p < Tn; p += 256) {
        int py = p >> 6, px = p & 63;
        float acc = 0.f;
        #pragma unroll
        for (int dy = 0; dy < 5; ++dy)
            #pragma unroll
            for (int dx = 0; dx < 5; ++dx)
                acc = fmaf(tile[(py + dy) * 68 + (px + dx)], wk[dy * 5 + dx], acc);
        unsigned short h, l;
        split_bf16(acc, h, l);
        oh[p] = h;
        ol[p] = l;
    }
}

// ---------------------------------------------------------------------------
// transpose a 4x4 u16 tile held across a lane quad (lane j = row j, uint2 = 4 cols)
// ---------------------------------------------------------------------------
__device__ __forceinline__ uint2 quad_transpose(uint2 v, int j) {
    unsigned int p0 = (unsigned int)__shfl_xor((int)v.x, 1);
    unsigned int p1 = (unsigned int)__shfl_xor((int)v.y, 1);
    unsigned int g0, g1;
    if ((j & 1) == 0) {
        g0 = (p0 << 16) | (v.x & 0xFFFFu);
        g1 = (p1 << 16) | (v.y & 0xFFFFu);
    } else {
        g0 = (v.x & 0xFFFF0000u) | (p0 >> 16);
        g1 = (v.y & 0xFFFF0000u) | (p1 >> 16);
    }
    unsigned int s0 = (unsigned int)__shfl_xor((int)g0, 2);
    unsigned int s1 = (unsigned int)__shfl_xor((int)g1, 2);
    uint2 f;
    if ((j & 2) == 0) { f.x = g0; f.y = s0; }
    else              { f.x = s1; f.y = g1; }
    return f;
}

// ---------------------------------------------------------------------------
// Kernel 2: split-bf16 MFMA GEMM.  Out[b][m][t] = sum_c W[m][c] * X[b][c][t]
// computed as Whi*Xhi + Whi*Xlo + Wlo*Xhi with v_mfma_f32_32x32x16_bf16.
// Block tile 128(M)x128(N), 4 waves (2x2) of 64x64, 2x2 frags of 32x32, BK=32.
// M=192 handled by row0 in {0,64}; rows 64..127 computed twice, stored once
// (wave-uniform mask). LDS tiles 16B-block XOR-swizzled -> conflict-free b128.
// ---------------------------------------------------------------------------
__global__ __launch_bounds__(256) void gemm_bf16x3(const unsigned short* __restrict__ Whi,
                                                   const unsigned short* __restrict__ Wlo,
                                                   const unsigned short* __restrict__ Xhi,
                                                   const unsigned short* __restrict__ Xlo,
                                                   float* __restrict__ Out) {
    __shared__ unsigned short Ah[128][40], Al[128][40];
    __shared__ unsigned short Bh[128][40], Bl[128][40];

    const int tid = threadIdx.x;
    const int l = tid & 63;
    const int w = tid >> 6;
    const int wm = w >> 1, wn = w & 1;
    const int row0 = blockIdx.y * 64;          // 0 or 64
    const int t0 = blockIdx.x * 128;
    const size_t xbase = (size_t)blockIdx.z * Cn * Tn;

    f32x16 acc[2][2];
    #pragma unroll
    for (int mf = 0; mf < 2; ++mf)
        #pragma unroll
        for (int nf = 0; nf < 2; ++nf)
            #pragma unroll
            for (int r = 0; r < 16; ++r) acc[mf][nf][r] = 0.f;

    for (int k0 = 0; k0 < Cn; k0 += 32) {
        // ---- stage A (W) tile: 128 rows x 32 c, hi+lo ----
        #pragma unroll
        for (int p = 0; p < 4; ++p) {
            int i = p * 256 + tid;
            int d = i >> 3, c4 = i & 7;
            size_t g = (size_t)(row0 + d) * Cn + k0 + c4 * 4;
            ushort4 vh = *(const ushort4*)&Whi[g];
            ushort4 vl = *(const ushort4*)&Wlo[g];
            int cbS = (((c4 >> 1) ^ ((d >> 3) & 3)) << 3) + ((c4 & 1) << 2);
            *(ushort4*)&Ah[d][cbS] = vh;
            *(ushort4*)&Al[d][cbS] = vl;
        }
        // ---- stage B (X) tile: 32 c x 128 t, transposed to [t][c], hi+lo ----
        #pragma unroll
        for (int p = 0; p < 4; ++p) {
            int idx = p * 64 + (tid >> 2);
            int j = tid & 3;
            int cq = idx >> 5, tq = idx & 31;
            size_t g = xbase + (size_t)(k0 + cq * 4 + j) * Tn + t0 + tq * 4;
            uint2 vh = *(const uint2*)&Xhi[g];
            uint2 vl = *(const uint2*)&Xlo[g];
            uint2 th = quad_transpose(vh, j);
            uint2 tl = quad_transpose(vl, j);
            int t = tq * 4 + j;
            int cbS = (((cq >> 1) ^ ((t >> 3) & 3)) << 3) + ((cq & 1) << 2);
            *(uint2*)&Bh[t][cbS] = th;
            *(uint2*)&Bl[t][cbS] = tl;
        }
        __syncthreads();

        // ---- fragments + MFMA ----
        bf16x8 afh[2][2], afl[2][2];
        #pragma unroll
        for (int mf = 0; mf < 2; ++mf)
            #pragma unroll
            for (int kh = 0; kh < 2; ++kh) {
                int d = wm * 64 + mf * 32 + (l & 31);
                int cb = (kh * 2 + (l >> 5)) ^ ((d >> 3) & 3);
                afh[mf][kh] = *(const bf16x8*)&Ah[d][cb * 8];
                afl[mf][kh] = *(const bf16x8*)&Al[d][cb * 8];
            }
        #pragma unroll
        for (int nf = 0; nf < 2; ++nf) {
            int t = wn * 64 + nf * 32 + (l & 31);
            int tb = (t >> 3) & 3;
            #pragma unroll
            for (int kh = 0; kh < 2; ++kh) {
                int cb = (kh * 2 + (l >> 5)) ^ tb;
                bf16x8 bfh = *(const bf16x8*)&Bh[t][cb * 8];
                bf16x8 bfl = *(const bf16x8*)&Bl[t][cb * 8];
                #pragma unroll
                for (int mf = 0; mf < 2; ++mf) {
                    acc[mf][nf] = __builtin_amdgcn_mfma_f32_32x32x16_bf16(afh[mf][kh], bfh, acc[mf][nf], 0, 0, 0);
                    acc[mf][nf] = __builtin_amdgcn_mfma_f32_32x32x16_bf16(afh[mf][kh], bfl, acc[mf][nf], 0, 0, 0);
                    acc[mf][nf] = __builtin_amdgcn_mfma_f32_32x32x16_bf16(afl[mf][kh], bfh, acc[mf][nf], 0, 0, 0);
                }
            }
        }
        __syncthreads();
    }

    // ---- epilogue: store (skip duplicated rows 64..127 for row0==64) ----
    if (row0 == 0 || wm == 1) {
        float* O = Out + (size_t)blockIdx.z * Cn * Tn;
        #pragma unroll
        for (int mf = 0; mf < 2; ++mf)
            #pragma unroll
            for (int nf = 0; nf < 2; ++nf) {
                int col = t0 + wn * 64 + nf * 32 + (l & 31);
                #pragma unroll
                for (int r = 0; r < 16; ++r) {
                    int row = row0 + wm * 64 + mf * 32 + (r & 3) + 8 * (r >> 2) + 4 * (l >> 5);
                    O[(size_t)row * Tn + col] = acc[mf][nf][r];
                }
            }
    }
}

// ---------------------------------------------------------------------------
// Kernel 3: bidirectional WKV + sigmoid(receptance); outputs split bf16 hi/lo.
// ---------------------------------------------------------------------------
__global__ __launch_bounds__(256) void wkv_kernel(const float* __restrict__ kg,
                                                  const float* __restrict__ vg,
                                                  const float* __restrict__ srlg,
                                                  const float* __restrict__ decay,
                                                  const float* __restrict__ boost,
                                                  unsigned short* __restrict__ yhi,
                                                  unsigned short* __restrict__ ylo) {
    const int row = blockIdx.x;       // b*C + d
    const int d = row % Cn;
    const float* kr = kg + (size_t)row * Tn;
    const float* vr = vg + (size_t)row * Tn;
    const float* sr = srlg + (size_t)row * Tn;
    unsigned short* yh = yhi + (size_t)row * Tn;
    unsigned short* yl = ylo + (size_t)row * Tn;

    const int tid = threadIdx.x;
    const int t0 = tid * 16;

    float kk[16], vv[16];
    #pragma unroll
    for (int j = 0; j < 16; j += 4) {
        *(float4*)&kk[j] = *(const float4*)&kr[t0 + j];
        *(float4*)&vv[j] = *(const float4*)&vr[t0 + j];
    }

    __shared__ float red[256];
    float lm = kk[0];
    #pragma unroll
    for (int j = 1; j < 16; ++j) lm = fmaxf(lm, kk[j]);
    red[tid] = lm;
    __syncthreads();
    for (int s = 128; s > 0; s >>= 1) {
        if (tid < s) red[tid] = fmaxf(red[tid], red[tid + s]);
        __syncthreads();
    }
    const float m = red[0];
    __syncthreads();

    const float ww = decay[d] * (1.0f / (float)Tn);
    const float u = boost[d] * (1.0f / (float)Tn);
    const float lam = expf(-ww);
    const float lam16 = expf(-16.0f * ww);

    float a[16];
    #pragma unroll
    for (int j = 0; j < 16; ++j) a[j] = expf(kk[j] - m);

    float SN = 0.f, SD = 0.f;
    #pragma unroll
    for (int j = 0; j < 16; ++j) { SN = fmaf(lam, SN, a[j] * vv[j]); SD = fmaf(lam, SD, a[j]); }
    float BN = 0.f, BD = 0.f;
    #pragma unroll
    for (int j = 15; j >= 0; --j) { BN = fmaf(lam, BN, a[j] * vv[j]); BD = fmaf(lam, BD, a[j]); }

    __shared__ float sN[2][256], sD[2][256];

    sN[0][tid] = SN; sD[0][tid] = SD;
    __syncthreads();
    int src = 0;
    float f = lam16;
    for (int o = 1; o < 256; o <<= 1) {
        float nN = sN[src][tid], nD = sD[src][tid];
        if (tid >= o) { nN = fmaf(f, sN[src][tid - o], nN); nD = fmaf(f, sD[src][tid - o], nD); }
        sN[src ^ 1][tid] = nN; sD[src ^ 1][tid] = nD;
        __syncthreads();
        src ^= 1; f = f * f;
    }
    const float CfN = (tid > 0) ? sN[src][tid - 1] : 0.f;
    const float CfD = (tid > 0) ? sD[src][tid - 1] : 0.f;
    __syncthreads();

    sN[0][tid] = BN; sD[0][tid] = BD;
    __syncthreads();
    src = 0; f = lam16;
    for (int o = 1; o < 256; o <<= 1) {
        float nN = sN[src][tid], nD = sD[src][tid];
        if (tid + o < 256) { nN = fmaf(f, sN[src][tid + o], nN); nD = fmaf(f, sD[src][tid + o], nD); }
        sN[src ^ 1][tid] = nN; sD[src ^ 1][tid] = nD;
        __syncthreads();
        src ^= 1; f = f * f;
    }
    const float CbN = (tid < 255) ? sN[src][tid + 1] : 0.f;
    const float CbD = (tid < 255) ? sD[src][tid + 1] : 0.f;

    float fN[16], fD[16];
    float cN = CfN, cD = CfD;
    #pragma unroll
    for (int j = 0; j < 16; ++j) {
        fN[j] = cN; fD[j] = cD;
        cN = fmaf(lam, cN, a[j] * vv[j]);
        cD = fmaf(lam, cD, a[j]);
    }

    float sl[16];
    #pragma unroll
    for (int j = 0; j < 16; j += 4) *(float4*)&sl[j] = *(const float4*)&sr[t0 + j];

    unsigned short oh[16], ol[16];
    float bN = CbN, bD = CbD;
    #pragma unroll
    for (int j = 15; j >= 0; --j) {
        const float es = expf(u + kk[j] - m);
        const float num = fN[j] + bN + es * vv[j];
        const float den = fD[j] + bD + es;
        const float y = num / den;
        const float sig = 1.0f / (1.0f + expf(-sl[j]));
        split_bf16(sig * y, oh[j], ol[j]);
        bN = fmaf(lam, bN, a[j] * vv[j]);
        bD = fmaf(lam, bD, a[j]);
    }

    unsigned int ph[8], pl[8];
    #pragma unroll
    for (int j = 0; j < 8; ++j) {
        ph[j] = (unsigned int)oh[2 * j] | ((unsigned int)oh[2 * j + 1] << 16);
        pl[j] = (unsigned int)ol[2 * j] | ((unsigned int)ol[2 * j + 1] << 16);
    }
    *(uint4*)&yh[t0]     = make_uint4(ph[0], ph[1], ph[2], ph[3]);
    *(uint4*)&yh[t0 + 8] = make_uint4(ph[4], ph[5], ph[6], ph[7]);
    *(uint4*)&yl[t0]     = make_uint4(pl[0], pl[1], pl[2], pl[3]);
    *(uint4*)&yl[t0 + 8] = make_uint4(pl[4], pl[5], pl[6], pl[7]);
}

// ---------------------------------------------------------------------------
extern "C" void kernel_launch(void* const* d_in, const int* in_sizes, int n_in,
                              void* d_out, int out_size, void* d_ws, size_t ws_size,
                              hipStream_t stream) {
    const float* x        = (const float*)d_in[0];
    const float* w_key    = (const float*)d_in[1];
    const float* w_value  = (const float*)d_in[2];
    const float* w_recept = (const float*)d_in[3];
    const float* w_out    = (const float*)d_in[4];
    const float* decay    = (const float*)d_in[5];
    const float* boost    = (const float*)d_in[6];
    const float* alpha    = (const float*)d_in[7];
    const float* dw1      = (const float*)d_in[8];
    const float* dw3      = (const float*)d_in[9];
    const float* dw5      = (const float*)d_in[10];

    const size_t S = (size_t)Bn * Cn * Tn;   // 6291456 elements
    char* wsb = (char*)d_ws;
    unsigned short* xs_hi = (unsigned short*)wsb;                  // S ushorts
    unsigned short* xs_lo = xs_hi + S;                             // S ushorts
    float* kb = (float*)(wsb + 2 * S * sizeof(unsigned short));    // S floats
    float* vb = kb + S;                                            // S floats
    unsigned short* wh = (unsigned short*)(vb + S);                // 4*36864
    unsigned short* wl = wh + 4 * 36864;                           // 4*36864
    float* srl = (float*)d_out;                                    // scratch until final GEMM
    float* out = (float*)d_out;

    wsplit_kernel<<<dim3(144, 4), 256, 0, stream>>>(w_key, w_value, w_recept, w_out, wh, wl);

    omni_kernel<<<dim3(Bn * Cn), 256, 0, stream>>>(x, alpha, dw1, dw3, dw5, xs_hi, xs_lo);

    gemm_bf16x3<<<dim3(Tn / 128, 2, Bn), 256, 0, stream>>>(wh + 0 * 36864, wl + 0 * 36864, xs_hi, xs_lo, kb);
    gemm_bf16x3<<<dim3(Tn / 128, 2, Bn), 256, 0, stream>>>(wh + 1 * 36864, wl + 1 * 36864, xs_hi, xs_lo, vb);
    gemm_bf16x3<<<dim3(Tn / 128, 2, Bn), 256, 0, stream>>>(wh + 2 * 36864, wl + 2 * 36864, xs_hi, xs_lo, srl);

    wkv_kernel<<<dim3(Bn * Cn), 256, 0, stream>>>(kb, vb, srl, decay, boost, xs_hi, xs_lo);

    gemm_bf16x3<<<dim3(Tn / 128, 2, Bn), 256, 0, stream>>>(wh + 3 * 36864, wl + 3 * 36864, xs_hi, xs_lo, out);
}

// Round 4
// 138.834 us; speedup vs baseline: 1.6375x; 1.1606x over previous
//
#include <hip/hip_runtime.h>
#include <math.h>

#define Cn 192
#define Bn 8
#define Tn 4096
#define HW 64

typedef __attribute__((ext_vector_type(8))) __bf16 bf16x8;
typedef __attribute__((ext_vector_type(16))) float f32x16;

__device__ __forceinline__ void split_bf16(float x, unsigned short &h, unsigned short &l) {
    unsigned int u = __float_as_uint(x);
    unsigned int uh = (u + 0x7FFFu + ((u >> 16) & 1u)) & 0xFFFF0000u;
    h = (unsigned short)(uh >> 16);
    float r = x - __uint_as_float(uh);
    unsigned int ur = __float_as_uint(r);
    l = (unsigned short)((ur + 0x7FFFu + ((ur >> 16) & 1u)) >> 16);
}

// ---------------------------------------------------------------------------
// Kernel 0: split the 4 weight matrices into bf16 hi/lo parts.
// ---------------------------------------------------------------------------
__global__ __launch_bounds__(256) void wsplit_kernel(const float* __restrict__ Wk,
                                                     const float* __restrict__ Wv,
                                                     const float* __restrict__ Wr,
                                                     const float* __restrict__ Wo,
                                                     unsigned short* __restrict__ wh,
                                                     unsigned short* __restrict__ wl) {
    const int idx = blockIdx.x * 256 + threadIdx.x;      // 0..36863
    const int mat = blockIdx.y;
    const float* src = (mat == 0) ? Wk : (mat == 1) ? Wv : (mat == 2) ? Wr : Wo;
    unsigned short h, l;
    split_bf16(src[idx], h, l);
    wh[(size_t)mat * 36864 + idx] = h;
    wl[(size_t)mat * 36864 + idx] = l;
}

// ---------------------------------------------------------------------------
// Kernel 1: omni_shift (fused 25-tap depthwise conv) -> split bf16 hi/lo out.
// Register-blocked: each thread does 2 segments of 8 outputs; LDS reads are
// 30 x ds_read_b128 per thread instead of 400 x ds_read_b32.
// ---------------------------------------------------------------------------
__global__ __launch_bounds__(256) void omni_kernel(const float* __restrict__ x,
                                                   const float* __restrict__ alpha,
                                                   const float* __restrict__ dw1,
                                                   const float* __restrict__ dw3,
                                                   const float* __restrict__ dw5,
                                                   unsigned short* __restrict__ xhi,
                                                   unsigned short* __restrict__ xlo) {
    const int plane = blockIdx.x;          // b*C + c
    const int c = plane % Cn;
    const float* xin = x + (size_t)plane * Tn;
    unsigned short* oh = xhi + (size_t)plane * Tn;
    unsigned short* ol = xlo + (size_t)plane * Tn;

    __shared__ float tile[68 * 68];
    __shared__ float wk[25];

    const int tid = threadIdx.x;
    if (tid == 0) {
        const float a0 = alpha[0], a1 = alpha[1], a2 = alpha[2], a3 = alpha[3];
        #pragma unroll
        for (int j = 0; j < 25; ++j) wk[j] = a3 * dw5[c * 25 + j];
        #pragma unroll
        for (int dy = 0; dy < 3; ++dy)
            #pragma unroll
            for (int dx = 0; dx < 3; ++dx)
                wk[(dy + 1) * 5 + (dx + 1)] += a2 * dw3[c * 9 + dy * 3 + dx];
        wk[12] += a1 * dw1[c] + a0;
    }
    for (int i = tid; i < 68 * 68; i += 256) {
        int r = i / 68, cc = i - r * 68;
        int gy = r - 2, gx = cc - 2;
        float v = 0.f;
        if (gy >= 0 && gy < HW && gx >= 0 && gx < HW) v = xin[gy * HW + gx];
        tile[i] = v;
    }
    __syncthreads();

    const int py = tid >> 3;          // 0..31
    const int px0 = (tid & 7) << 3;   // 0,8,..,56

    #pragma unroll
    for (int half = 0; half < 2; ++half) {
        const int y = py + half * 32;
        float row[5][12];
        #pragma unroll
        for (int dy = 0; dy < 5; ++dy) {
            const float4* rp = (const float4*)&tile[(y + dy) * 68 + px0];  // 16B aligned (272B row stride)
            float4 r0 = rp[0], r1 = rp[1], r2 = rp[2];
            row[dy][0] = r0.x; row[dy][1] = r0.y; row[dy][2]  = r0.z; row[dy][3]  = r0.w;
            row[dy][4] = r1.x; row[dy][5] = r1.y; row[dy][6]  = r1.z; row[dy][7]  = r1.w;
            row[dy][8] = r2.x; row[dy][9] = r2.y; row[dy][10] = r2.z; row[dy][11] = r2.w;
        }
        unsigned int ph[4], pl[4];
        #pragma unroll
        for (int jj = 0; jj < 8; ++jj) {
            float acc = 0.f;
            #pragma unroll
            for (int dy = 0; dy < 5; ++dy)
                #pragma unroll
                for (int dx = 0; dx < 5; ++dx)
                    acc = fmaf(row[dy][jj + dx], wk[dy * 5 + dx], acc);
            unsigned short h, l2;
            split_bf16(acc, h, l2);
            if (jj & 1) { ph[jj >> 1] |= ((unsigned int)h) << 16; pl[jj >> 1] |= ((unsigned int)l2) << 16; }
            else        { ph[jj >> 1] = h;                        pl[jj >> 1] = l2; }
        }
        *(uint4*)&oh[y * 64 + px0] = make_uint4(ph[0], ph[1], ph[2], ph[3]);
        *(uint4*)&ol[y * 64 + px0] = make_uint4(pl[0], pl[1], pl[2], pl[3]);
    }
}

// ---------------------------------------------------------------------------
// transpose a 4x4 u16 tile held across a lane quad (lane j = row j, uint2 = 4 cols)
// ---------------------------------------------------------------------------
__device__ __forceinline__ uint2 quad_transpose(uint2 v, int j) {
    unsigned int p0 = (unsigned int)__shfl_xor((int)v.x, 1);
    unsigned int p1 = (unsigned int)__shfl_xor((int)v.y, 1);
    unsigned int g0, g1;
    if ((j & 1) == 0) {
        g0 = (p0 << 16) | (v.x & 0xFFFFu);
        g1 = (p1 << 16) | (v.y & 0xFFFFu);
    } else {
        g0 = (v.x & 0xFFFF0000u) | (p0 >> 16);
        g1 = (v.y & 0xFFFF0000u) | (p1 >> 16);
    }
    unsigned int s0 = (unsigned int)__shfl_xor((int)g0, 2);
    unsigned int s1 = (unsigned int)__shfl_xor((int)g1, 2);
    uint2 f;
    if ((j & 2) == 0) { f.x = g0; f.y = s0; }
    else              { f.x = s1; f.y = g1; }
    return f;
}

// ---------------------------------------------------------------------------
// Kernel 2: FUSED k/v/sr projection, split-bf16 MFMA.
// Out_m[b][d][t] = sum_c W_m[d][c] * X[b][c][t], m in {key, value, recept},
// each as Whi*Xhi + Whi*Xlo + Wlo*Xhi with v_mfma_f32_32x32x16_bf16.
// Block tile 64(M)x128(N), 4 waves (2x2) each 32x64 per matrix, BK=32.
// M=192 = 3 exact 64-row tiles (no padding waste). X staged once per K-step,
// each B fragment feeds 9 MFMAs. LDS 16B-block XOR-swizzled.
// ---------------------------------------------------------------------------
__global__ __launch_bounds__(256) void proj3_mfma(const unsigned short* __restrict__ wh,
                                                  const unsigned short* __restrict__ wl,
                                                  const unsigned short* __restrict__ Xhi,
                                                  const unsigned short* __restrict__ Xlo,
                                                  float* __restrict__ kout,
                                                  float* __restrict__ vout,
                                                  float* __restrict__ rout) {
    __shared__ unsigned short Ah[3][64][40], Al[3][64][40];
    __shared__ unsigned short Bh[128][40], Bl[128][40];

    const int tid = threadIdx.x;
    const int l = tid & 63;
    const int w = tid >> 6;
    const int wm = w >> 1, wn = w & 1;
    const int m0 = blockIdx.y * 64;            // 0,64,128
    const int t0 = blockIdx.x * 128;
    const size_t xbase = (size_t)blockIdx.z * Cn * Tn;

    f32x16 acc[3][2];
    #pragma unroll
    for (int mat = 0; mat < 3; ++mat)
        #pragma unroll
        for (int nf = 0; nf < 2; ++nf)
            #pragma unroll
            for (int r = 0; r < 16; ++r) acc[mat][nf][r] = 0.f;

    for (int k0 = 0; k0 < Cn; k0 += 32) {
        // ---- stage A: 3 mats x 64 rows x 32 c (hi+lo) ----
        #pragma unroll
        for (int p = 0; p < 6; ++p) {
            const int mat = p >> 1;                    // compile-time per unrolled p
            const int r = ((p & 1) << 8) + tid;        // 0..511
            const int d = r >> 3, c4 = r & 7;
            size_t g = (size_t)mat * 36864 + (size_t)(m0 + d) * Cn + k0 + c4 * 4;
            ushort4 vh = *(const ushort4*)&wh[g];
            ushort4 vl = *(const ushort4*)&wl[g];
            int cbS = (((c4 >> 1) ^ ((d >> 3) & 3)) << 3) + ((c4 & 1) << 2);
            *(ushort4*)&Ah[mat][d][cbS] = vh;
            *(ushort4*)&Al[mat][d][cbS] = vl;
        }
        // ---- stage B: 32 c x 128 t, quad-transposed to [t][c] (hi+lo) ----
        #pragma unroll
        for (int p = 0; p < 4; ++p) {
            int idx = p * 64 + (tid >> 2);
            int j = tid & 3;
            int cq = idx >> 5, tq = idx & 31;
            size_t g = xbase + (size_t)(k0 + cq * 4 + j) * Tn + t0 + tq * 4;
            uint2 vh2 = *(const uint2*)&Xhi[g];
            uint2 vl2 = *(const uint2*)&Xlo[g];
            uint2 th = quad_transpose(vh2, j);
            uint2 tl = quad_transpose(vl2, j);
            int t = tq * 4 + j;
            int cbS = (((cq >> 1) ^ ((t >> 3) & 3)) << 3) + ((cq & 1) << 2);
            *(uint2*)&Bh[t][cbS] = th;
            *(uint2*)&Bl[t][cbS] = tl;
        }
        __syncthreads();

        // ---- A fragments (reused across nf) ----
        bf16x8 afh[3][2], afl[3][2];
        const int d = wm * 32 + (l & 31);
        const int db = (d >> 3) & 3;
        #pragma unroll
        for (int mat = 0; mat < 3; ++mat)
            #pragma unroll
            for (int kh = 0; kh < 2; ++kh) {
                int cb = (kh * 2 + (l >> 5)) ^ db;
                afh[mat][kh] = *(const bf16x8*)&Ah[mat][d][cb * 8];
                afl[mat][kh] = *(const bf16x8*)&Al[mat][d][cb * 8];
            }
        // ---- B fragments + MFMA ----
        #pragma unroll
        for (int nf = 0; nf < 2; ++nf) {
            int t = wn * 64 + nf * 32 + (l & 31);
            int tb = (t >> 3) & 3;
            #pragma unroll
            for (int kh = 0; kh < 2; ++kh) {
                int cb = (kh * 2 + (l >> 5)) ^ tb;
                bf16x8 bfh = *(const bf16x8*)&Bh[t][cb * 8];
                bf16x8 bfl = *(const bf16x8*)&Bl[t][cb * 8];
                #pragma unroll
                for (int mat = 0; mat < 3; ++mat) {
                    acc[mat][nf] = __builtin_amdgcn_mfma_f32_32x32x16_bf16(afh[mat][kh], bfh, acc[mat][nf], 0, 0, 0);
                    acc[mat][nf] = __builtin_amdgcn_mfma_f32_32x32x16_bf16(afh[mat][kh], bfl, acc[mat][nf], 0, 0, 0);
                    acc[mat][nf] = __builtin_amdgcn_mfma_f32_32x32x16_bf16(afl[mat][kh], bfh, acc[mat][nf], 0, 0, 0);
                }
            }
        }
        __syncthreads();
    }

    // ---- epilogue ----
    float* outs[3] = {kout, vout, rout};
    #pragma unroll
    for (int mat = 0; mat < 3; ++mat) {
        float* O = outs[mat] + (size_t)blockIdx.z * Cn * Tn;
        #pragma unroll
        for (int nf = 0; nf < 2; ++nf) {
            int col = t0 + wn * 64 + nf * 32 + (l & 31);
            #pragma unroll
            for (int r = 0; r < 16; ++r) {
                int row = m0 + wm * 32 + (r & 3) + 8 * (r >> 2) + 4 * (l >> 5);
                O[(size_t)row * Tn + col] = acc[mat][nf][r];
            }
        }
    }
}

// ---------------------------------------------------------------------------
// Kernel 3: split-bf16 MFMA GEMM (single matrix) for the output projection.
// Block tile 128x128, 4 waves of 64x64, 2x2 frags of 32x32, BK=32.
// ---------------------------------------------------------------------------
__global__ __launch_bounds__(256) void gemm_bf16x3(const unsigned short* __restrict__ Whi,
                                                   const unsigned short* __restrict__ Wlo,
                                                   const unsigned short* __restrict__ Xhi,
                                                   const unsigned short* __restrict__ Xlo,
                                                   float* __restrict__ Out) {
    __shared__ unsigned short Ah[128][40], Al[128][40];
    __shared__ unsigned short Bh[128][40], Bl[128][40];

    const int tid = threadIdx.x;
    const int l = tid & 63;
    const int w = tid >> 6;
    const int wm = w >> 1, wn = w & 1;
    const int row0 = blockIdx.y * 64;          // 0 or 64
    const int t0 = blockIdx.x * 128;
    const size_t xbase = (size_t)blockIdx.z * Cn * Tn;

    f32x16 acc[2][2];
    #pragma unroll
    for (int mf = 0; mf < 2; ++mf)
        #pragma unroll
        for (int nf = 0; nf < 2; ++nf)
            #pragma unroll
            for (int r = 0; r < 16; ++r) acc[mf][nf][r] = 0.f;

    for (int k0 = 0; k0 < Cn; k0 += 32) {
        #pragma unroll
        for (int p = 0; p < 4; ++p) {
            int i = p * 256 + tid;
            int d = i >> 3, c4 = i & 7;
            size_t g = (size_t)(row0 + d) * Cn + k0 + c4 * 4;
            ushort4 vh = *(const ushort4*)&Whi[g];
            ushort4 vl = *(const ushort4*)&Wlo[g];
            int cbS = (((c4 >> 1) ^ ((d >> 3) & 3)) << 3) + ((c4 & 1) << 2);
            *(ushort4*)&Ah[d][cbS] = vh;
            *(ushort4*)&Al[d][cbS] = vl;
        }
        #pragma unroll
        for (int p = 0; p < 4; ++p) {
            int idx = p * 64 + (tid >> 2);
            int j = tid & 3;
            int cq = idx >> 5, tq = idx & 31;
            size_t g = xbase + (size_t)(k0 + cq * 4 + j) * Tn + t0 + tq * 4;
            uint2 vh = *(const uint2*)&Xhi[g];
            uint2 vl = *(const uint2*)&Xlo[g];
            uint2 th = quad_transpose(vh, j);
            uint2 tl = quad_transpose(vl, j);
            int t = tq * 4 + j;
            int cbS = (((cq >> 1) ^ ((t >> 3) & 3)) << 3) + ((cq & 1) << 2);
            *(uint2*)&Bh[t][cbS] = th;
            *(uint2*)&Bl[t][cbS] = tl;
        }
        __syncthreads();

        bf16x8 afh[2][2], afl[2][2];
        #pragma unroll
        for (int mf = 0; mf < 2; ++mf)
            #pragma unroll
            for (int kh = 0; kh < 2; ++kh) {
                int d = wm * 64 + mf * 32 + (l & 31);
                int cb = (kh * 2 + (l >> 5)) ^ ((d >> 3) & 3);
                afh[mf][kh] = *(const bf16x8*)&Ah[d][cb * 8];
                afl[mf][kh] = *(const bf16x8*)&Al[d][cb * 8];
            }
        #pragma unroll
        for (int nf = 0; nf < 2; ++nf) {
            int t = wn * 64 + nf * 32 + (l & 31);
            int tb = (t >> 3) & 3;
            #pragma unroll
            for (int kh = 0; kh < 2; ++kh) {
                int cb = (kh * 2 + (l >> 5)) ^ tb;
                bf16x8 bfh = *(const bf16x8*)&Bh[t][cb * 8];
                bf16x8 bfl = *(const bf16x8*)&Bl[t][cb * 8];
                #pragma unroll
                for (int mf = 0; mf < 2; ++mf) {
                    acc[mf][nf] = __builtin_amdgcn_mfma_f32_32x32x16_bf16(afh[mf][kh], bfh, acc[mf][nf], 0, 0, 0);
                    acc[mf][nf] = __builtin_amdgcn_mfma_f32_32x32x16_bf16(afh[mf][kh], bfl, acc[mf][nf], 0, 0, 0);
                    acc[mf][nf] = __builtin_amdgcn_mfma_f32_32x32x16_bf16(afl[mf][kh], bfh, acc[mf][nf], 0, 0, 0);
                }
            }
        }
        __syncthreads();
    }

    if (row0 == 0 || wm == 1) {
        float* O = Out + (size_t)blockIdx.z * Cn * Tn;
        #pragma unroll
        for (int mf = 0; mf < 2; ++mf)
            #pragma unroll
            for (int nf = 0; nf < 2; ++nf) {
                int col = t0 + wn * 64 + nf * 32 + (l & 31);
                #pragma unroll
                for (int r = 0; r < 16; ++r) {
                    int row = row0 + wm * 64 + mf * 32 + (r & 3) + 8 * (r >> 2) + 4 * (l >> 5);
                    O[(size_t)row * Tn + col] = acc[mf][nf][r];
                }
            }
    }
}

// ---------------------------------------------------------------------------
// Kernel 4: bidirectional WKV + sigmoid(receptance); outputs split bf16 hi/lo.
// ---------------------------------------------------------------------------
__global__ __launch_bounds__(256) void wkv_kernel(const float* __restrict__ kg,
                                                  const float* __restrict__ vg,
                                                  const float* __restrict__ srlg,
                                                  const float* __restrict__ decay,
                                                  const float* __restrict__ boost,
                                                  unsigned short* __restrict__ yhi,
                                                  unsigned short* __restrict__ ylo) {
    const int row = blockIdx.x;       // b*C + d
    const int d = row % Cn;
    const float* kr = kg + (size_t)row * Tn;
    const float* vr = vg + (size_t)row * Tn;
    const float* sr = srlg + (size_t)row * Tn;
    unsigned short* yh = yhi + (size_t)row * Tn;
    unsigned short* yl = ylo + (size_t)row * Tn;

    const int tid = threadIdx.x;
    const int t0 = tid * 16;

    float kk[16], vv[16];
    #pragma unroll
    for (int j = 0; j < 16; j += 4) {
        *(float4*)&kk[j] = *(const float4*)&kr[t0 + j];
        *(float4*)&vv[j] = *(const float4*)&vr[t0 + j];
    }

    __shared__ float red[256];
    float lm = kk[0];
    #pragma unroll
    for (int j = 1; j < 16; ++j) lm = fmaxf(lm, kk[j]);
    red[tid] = lm;
    __syncthreads();
    for (int s = 128; s > 0; s >>= 1) {
        if (tid < s) red[tid] = fmaxf(red[tid], red[tid + s]);
        __syncthreads();
    }
    const float m = red[0];
    __syncthreads();

    const float ww = decay[d] * (1.0f / (float)Tn);
    const float u = boost[d] * (1.0f / (float)Tn);
    const float lam = expf(-ww);
    const float lam16 = expf(-16.0f * ww);

    float a[16];
    #pragma unroll
    for (int j = 0; j < 16; ++j) a[j] = expf(kk[j] - m);

    float SN = 0.f, SD = 0.f;
    #pragma unroll
    for (int j = 0; j < 16; ++j) { SN = fmaf(lam, SN, a[j] * vv[j]); SD = fmaf(lam, SD, a[j]); }
    float BN = 0.f, BD = 0.f;
    #pragma unroll
    for (int j = 15; j >= 0; --j) { BN = fmaf(lam, BN, a[j] * vv[j]); BD = fmaf(lam, BD, a[j]); }

    __shared__ float sN[2][256], sD[2][256];

    sN[0][tid] = SN; sD[0][tid] = SD;
    __syncthreads();
    int src = 0;
    float f = lam16;
    for (int o = 1; o < 256; o <<= 1) {
        float nN = sN[src][tid], nD = sD[src][tid];
        if (tid >= o) { nN = fmaf(f, sN[src][tid - o], nN); nD = fmaf(f, sD[src][tid - o], nD); }
        sN[src ^ 1][tid] = nN; sD[src ^ 1][tid] = nD;
        __syncthreads();
        src ^= 1; f = f * f;
    }
    const float CfN = (tid > 0) ? sN[src][tid - 1] : 0.f;
    const float CfD = (tid > 0) ? sD[src][tid - 1] : 0.f;
    __syncthreads();

    sN[0][tid] = BN; sD[0][tid] = BD;
    __syncthreads();
    src = 0; f = lam16;
    for (int o = 1; o < 256; o <<= 1) {
        float nN = sN[src][tid], nD = sD[src][tid];
        if (tid + o < 256) { nN = fmaf(f, sN[src][tid + o], nN); nD = fmaf(f, sD[src][tid + o], nD); }
        sN[src ^ 1][tid] = nN; sD[src ^ 1][tid] = nD;
        __syncthreads();
        src ^= 1; f = f * f;
    }
    const float CbN = (tid < 255) ? sN[src][tid + 1] : 0.f;
    const float CbD = (tid < 255) ? sD[src][tid + 1] : 0.f;

    float fN[16], fD[16];
    float cN = CfN, cD = CfD;
    #pragma unroll
    for (int j = 0; j < 16; ++j) {
        fN[j] = cN; fD[j] = cD;
        cN = fmaf(lam, cN, a[j] * vv[j]);
        cD = fmaf(lam, cD, a[j]);
    }

    float sl[16];
    #pragma unroll
    for (int j = 0; j < 16; j += 4) *(float4*)&sl[j] = *(const float4*)&sr[t0 + j];

    unsigned short oh[16], ol[16];
    float bN = CbN, bD = CbD;
    #pragma unroll
    for (int j = 15; j >= 0; --j) {
        const float es = expf(u + kk[j] - m);
        const float num = fN[j] + bN + es * vv[j];
        const float den = fD[j] + bD + es;
        const float y = num / den;
        const float sig = 1.0f / (1.0f + expf(-sl[j]));
        split_bf16(sig * y, oh[j], ol[j]);
        bN = fmaf(lam, bN, a[j] * vv[j]);
        bD = fmaf(lam, bD, a[j]);
    }

    unsigned int ph[8], pl[8];
    #pragma unroll
    for (int j = 0; j < 8; ++j) {
        ph[j] = (unsigned int)oh[2 * j] | ((unsigned int)oh[2 * j + 1] << 16);
        pl[j] = (unsigned int)ol[2 * j] | ((unsigned int)ol[2 * j + 1] << 16);
    }
    *(uint4*)&yh[t0]     = make_uint4(ph[0], ph[1], ph[2], ph[3]);
    *(uint4*)&yh[t0 + 8] = make_uint4(ph[4], ph[5], ph[6], ph[7]);
    *(uint4*)&yl[t0]     = make_uint4(pl[0], pl[1], pl[2], pl[3]);
    *(uint4*)&yl[t0 + 8] = make_uint4(pl[4], pl[5], pl[6], pl[7]);
}

// ---------------------------------------------------------------------------
extern "C" void kernel_launch(void* const* d_in, const int* in_sizes, int n_in,
                              void* d_out, int out_size, void* d_ws, size_t ws_size,
                              hipStream_t stream) {
    const float* x        = (const float*)d_in[0];
    const float* w_key    = (const float*)d_in[1];
    const float* w_value  = (const float*)d_in[2];
    const float* w_recept = (const float*)d_in[3];
    const float* w_out    = (const float*)d_in[4];
    const float* decay    = (const float*)d_in[5];
    const float* boost    = (const float*)d_in[6];
    const float* alpha    = (const float*)d_in[7];
    const float* dw1      = (const float*)d_in[8];
    const float* dw3      = (const float*)d_in[9];
    const float* dw5      = (const float*)d_in[10];

    const size_t S = (size_t)Bn * Cn * Tn;   // 6291456 elements
    char* wsb = (char*)d_ws;
    unsigned short* xs_hi = (unsigned short*)wsb;                  // S ushorts
    unsigned short* xs_lo = xs_hi + S;                             // S ushorts
    float* kb = (float*)(wsb + 2 * S * sizeof(unsigned short));    // S floats
    float* vb = kb + S;                                            // S floats
    unsigned short* wh = (unsigned short*)(vb + S);                // 4*36864
    unsigned short* wl = wh + 4 * 36864;                           // 4*36864
    float* srl = (float*)d_out;                                    // scratch until final GEMM
    float* out = (float*)d_out;

    wsplit_kernel<<<dim3(144, 4), 256, 0, stream>>>(w_key, w_value, w_recept, w_out, wh, wl);

    omni_kernel<<<dim3(Bn * Cn), 256, 0, stream>>>(x, alpha, dw1, dw3, dw5, xs_hi, xs_lo);

    proj3_mfma<<<dim3(Tn / 128, 3, Bn), 256, 0, stream>>>(wh, wl, xs_hi, xs_lo, kb, vb, srl);

    wkv_kernel<<<dim3(Bn * Cn), 256, 0, stream>>>(kb, vb, srl, decay, boost, xs_hi, xs_lo);

    gemm_bf16x3<<<dim3(Tn / 128, 2, Bn), 256, 0, stream>>>(wh + 3 * 36864, wl + 3 * 36864, xs_hi, xs_lo, out);
}

// Round 5
// 122.788 us; speedup vs baseline: 1.8515x; 1.1307x over previous
//
#include <hip/hip_runtime.h>
#include <math.h>

#define Cn 192
#define Bn 8
#define Tn 4096
#define HW 64

typedef unsigned short u16;
typedef unsigned int u32;
typedef __attribute__((ext_vector_type(8))) __bf16 bf16x8;
typedef __attribute__((ext_vector_type(16))) float f32x16;

__device__ __forceinline__ void gload16(const void* g, void* l) {
    __builtin_amdgcn_global_load_lds(
        (const __attribute__((address_space(1))) void*)g,
        (__attribute__((address_space(3))) void*)l, 16, 0, 0);
}

__device__ __forceinline__ void split_bf16(float x, u16 &h, u16 &l) {
    u32 u = __float_as_uint(x);
    u32 uh = (u + 0x7FFFu + ((u >> 16) & 1u)) & 0xFFFF0000u;
    h = (u16)(uh >> 16);
    float r = x - __uint_as_float(uh);
    u32 ur = __float_as_uint(r);
    l = (u16)((ur + 0x7FFFu + ((ur >> 16) & 1u)) >> 16);
}

// ---------------------------------------------------------------------------
// Kernel 0: split the 4 weight matrices into bf16 hi/lo parts (stacked rows).
// ---------------------------------------------------------------------------
__global__ __launch_bounds__(256) void wsplit_kernel(const float* __restrict__ Wk,
                                                     const float* __restrict__ Wv,
                                                     const float* __restrict__ Wr,
                                                     const float* __restrict__ Wo,
                                                     u16* __restrict__ wh,
                                                     u16* __restrict__ wl) {
    const int idx = blockIdx.x * 256 + threadIdx.x;      // 0..36863
    const int mat = blockIdx.y;
    const float* src = (mat == 0) ? Wk : (mat == 1) ? Wv : (mat == 2) ? Wr : Wo;
    u16 h, l;
    split_bf16(src[idx], h, l);
    wh[(size_t)mat * 36864 + idx] = h;
    wl[(size_t)mat * 36864 + idx] = l;
}

// ---------------------------------------------------------------------------
// Kernel 1: omni_shift (fused 25-tap depthwise conv) -> split bf16 hi/lo out.
// ---------------------------------------------------------------------------
__global__ __launch_bounds__(256) void omni_kernel(const float* __restrict__ x,
                                                   const float* __restrict__ alpha,
                                                   const float* __restrict__ dw1,
                                                   const float* __restrict__ dw3,
                                                   const float* __restrict__ dw5,
                                                   u16* __restrict__ xhi,
                                                   u16* __restrict__ xlo) {
    const int plane = blockIdx.x;          // b*C + c
    const int c = plane % Cn;
    const float* xin = x + (size_t)plane * Tn;
    u16* oh = xhi + (size_t)plane * Tn;
    u16* ol = xlo + (size_t)plane * Tn;

    __shared__ float tile[68 * 68];
    __shared__ float wk[25];

    const int tid = threadIdx.x;
    if (tid == 0) {
        const float a0 = alpha[0], a1 = alpha[1], a2 = alpha[2], a3 = alpha[3];
        #pragma unroll
        for (int j = 0; j < 25; ++j) wk[j] = a3 * dw5[c * 25 + j];
        #pragma unroll
        for (int dy = 0; dy < 3; ++dy)
            #pragma unroll
            for (int dx = 0; dx < 3; ++dx)
                wk[(dy + 1) * 5 + (dx + 1)] += a2 * dw3[c * 9 + dy * 3 + dx];
        wk[12] += a1 * dw1[c] + a0;
    }
    for (int i = tid; i < 68 * 68; i += 256) {
        int r = i / 68, cc = i - r * 68;
        int gy = r - 2, gx = cc - 2;
        float v = 0.f;
        if (gy >= 0 && gy < HW && gx >= 0 && gx < HW) v = xin[gy * HW + gx];
        tile[i] = v;
    }
    __syncthreads();

    const int py = tid >> 3;          // 0..31
    const int px0 = (tid & 7) << 3;   // 0,8,..,56

    #pragma unroll
    for (int half = 0; half < 2; ++half) {
        const int y = py + half * 32;
        float row[5][12];
        #pragma unroll
        for (int dy = 0; dy < 5; ++dy) {
            const float4* rp = (const float4*)&tile[(y + dy) * 68 + px0];
            float4 r0 = rp[0], r1 = rp[1], r2 = rp[2];
            row[dy][0] = r0.x; row[dy][1] = r0.y; row[dy][2]  = r0.z; row[dy][3]  = r0.w;
            row[dy][4] = r1.x; row[dy][5] = r1.y; row[dy][6]  = r1.z; row[dy][7]  = r1.w;
            row[dy][8] = r2.x; row[dy][9] = r2.y; row[dy][10] = r2.z; row[dy][11] = r2.w;
        }
        u32 ph[4], pl[4];
        #pragma unroll
        for (int jj = 0; jj < 8; ++jj) {
            float acc = 0.f;
            #pragma unroll
            for (int dy = 0; dy < 5; ++dy)
                #pragma unroll
                for (int dx = 0; dx < 5; ++dx)
                    acc = fmaf(row[dy][jj + dx], wk[dy * 5 + dx], acc);
            u16 h, l2;
            split_bf16(acc, h, l2);
            if (jj & 1) { ph[jj >> 1] |= ((u32)h) << 16; pl[jj >> 1] |= ((u32)l2) << 16; }
            else        { ph[jj >> 1] = h;               pl[jj >> 1] = l2; }
        }
        *(uint4*)&oh[y * 64 + px0] = make_uint4(ph[0], ph[1], ph[2], ph[3]);
        *(uint4*)&ol[y * 64 + px0] = make_uint4(pl[0], pl[1], pl[2], pl[3]);
    }
}

// ---------------------------------------------------------------------------
// Kernel 2: transpose [b][192][4096] -> [b][4096][192] for both hi and lo.
// Tile 32c x 128t; pack c-pairs into u32 in LDS; coalesced uint4 writes.
// ---------------------------------------------------------------------------
__global__ __launch_bounds__(256) void transpose_kernel(const u16* __restrict__ ih,
                                                        const u16* __restrict__ il,
                                                        u16* __restrict__ oh,
                                                        u16* __restrict__ ol) {
    __shared__ u32 T[2][128][21];     // pad 21 -> ~4-way worst on writes
    const int tid = threadIdx.x;
    const size_t ib = (size_t)blockIdx.z * Cn * Tn;
    const int c0 = blockIdx.y * 32, t0 = blockIdx.x * 128;

    {
        const int c2 = tid >> 4;            // 0..15 (c-pair)
        const int tc = (tid & 15) * 8;      // t offset 0..120
        const size_t ge = ib + (size_t)(c0 + 2 * c2) * Tn + t0 + tc;
        uint4 evh = *(const uint4*)&ih[ge];
        uint4 odh = *(const uint4*)&ih[ge + Tn];
        uint4 evl = *(const uint4*)&il[ge];
        uint4 odl = *(const uint4*)&il[ge + Tn];
        const u32 eh4[4] = {evh.x, evh.y, evh.z, evh.w};
        const u32 oh4[4] = {odh.x, odh.y, odh.z, odh.w};
        const u32 el4[4] = {evl.x, evl.y, evl.z, evl.w};
        const u32 ol4[4] = {odl.x, odl.y, odl.z, odl.w};
        #pragma unroll
        for (int q = 0; q < 4; ++q) {
            T[0][tc + 2 * q    ][c2] = (eh4[q] & 0xFFFFu) | (oh4[q] << 16);
            T[0][tc + 2 * q + 1][c2] = (eh4[q] >> 16) | (oh4[q] & 0xFFFF0000u);
            T[1][tc + 2 * q    ][c2] = (el4[q] & 0xFFFFu) | (ol4[q] << 16);
            T[1][tc + 2 * q + 1][c2] = (el4[q] >> 16) | (ol4[q] & 0xFFFF0000u);
        }
    }
    __syncthreads();
    {
        const int t = tid >> 1;
        const int hf = tid & 1;
        u32 wv[8][2];
        #pragma unroll
        for (int q = 0; q < 8; ++q) {
            wv[q][0] = T[0][t][hf * 8 + q];
            wv[q][1] = T[1][t][hf * 8 + q];
        }
        const size_t go = ib + (size_t)(t0 + t) * Cn + c0 + hf * 16;
        *(uint4*)&oh[go]     = make_uint4(wv[0][0], wv[1][0], wv[2][0], wv[3][0]);
        *(uint4*)&oh[go + 8] = make_uint4(wv[4][0], wv[5][0], wv[6][0], wv[7][0]);
        *(uint4*)&ol[go]     = make_uint4(wv[0][1], wv[1][1], wv[2][1], wv[3][1]);
        *(uint4*)&ol[go + 8] = make_uint4(wv[4][1], wv[5][1], wv[6][1], wv[7][1]);
    }
}

// ---------------------------------------------------------------------------
// Kernel 3: split-bf16 MFMA GEMM, global_load_lds staged, double-buffered.
// Out_m[b][row][t] = sum_c W[wrow0 + m*192 + m0 + row][c] * Xt[b][t][c]
// Block: NM*64 output rows x 128 t, 4 waves (2x2), BK=32, 6 K-steps.
// LDS linear dest (gload_lds) + inverse-swizzled global source; frag reads
// use cb ^ ((row>>1)&3) -> conflict-free ds_read_b128.
// ---------------------------------------------------------------------------
template<int NM>
__global__ __launch_bounds__(256) void gemm_mfma(const u16* __restrict__ wh,
                                                 const u16* __restrict__ wl,
                                                 const u16* __restrict__ Xh,
                                                 const u16* __restrict__ Xl,
                                                 float* __restrict__ O0,
                                                 float* __restrict__ O1,
                                                 float* __restrict__ O2,
                                                 int wrow0) {
    constexpr int AR  = NM * 64;        // A rows per block
    constexpr int ASZ = AR * 32;        // u16 per A array per K-step
    constexpr int BSZ = 128 * 32;       // u16 per B array per K-step
    constexpr int BUF = 2 * ASZ + 2 * BSZ;
    __shared__ u16 lds[2][BUF];

    const int tid  = threadIdx.x;
    const int l    = tid & 63;
    const int wave = tid >> 6;
    const int wm   = wave >> 1, wn = wave & 1;
    const int m0   = blockIdx.y * 64;
    const int t0   = blockIdx.x * 128;
    const size_t xb = (size_t)blockIdx.z * Cn * Tn;

    f32x16 acc[NM][2];
    #pragma unroll
    for (int m = 0; m < NM; ++m)
        #pragma unroll
        for (int nf = 0; nf < 2; ++nf)
            #pragma unroll
            for (int r = 0; r < 16; ++r) acc[m][nf][r] = 0.f;

    auto stage = [&](int bf, int k0) {
        u16* Ah = &lds[bf][0];
        u16* Al = &lds[bf][ASZ];
        u16* Bh = &lds[bf][2 * ASZ];
        u16* Bl = &lds[bf][2 * ASZ + BSZ];
        #pragma unroll
        for (int i = 0; i < NM; ++i) {
            int idx = i * 256 + tid;
            int row = idx >> 2;
            int cb  = (idx & 3) ^ ((row >> 1) & 3);
            int grow = wrow0 + (row >> 6) * 192 + m0 + (row & 63);
            int dst = (i * 256 + wave * 64) * 8;
            gload16(wh + (size_t)grow * Cn + k0 + cb * 8, Ah + dst);
            gload16(wl + (size_t)grow * Cn + k0 + cb * 8, Al + dst);
        }
        #pragma unroll
        for (int i = 0; i < 2; ++i) {
            int idx = i * 256 + tid;
            int tr  = idx >> 2;
            int cb  = (idx & 3) ^ ((tr >> 1) & 3);
            int dst = (i * 256 + wave * 64) * 8;
            gload16(Xh + xb + (size_t)(t0 + tr) * Cn + k0 + cb * 8, Bh + dst);
            gload16(Xl + xb + (size_t)(t0 + tr) * Cn + k0 + cb * 8, Bl + dst);
        }
    };

    auto compute = [&](int bf) {
        const u16* Ah = &lds[bf][0];
        const u16* Al = &lds[bf][ASZ];
        const u16* Bh = &lds[bf][2 * ASZ];
        const u16* Bl = &lds[bf][2 * ASZ + BSZ];
        #pragma unroll
        for (int kh = 0; kh < 2; ++kh) {
            const int cbb = kh * 2 + (l >> 5);
            bf16x8 ah[NM], al[NM];
            #pragma unroll
            for (int m = 0; m < NM; ++m) {
                int r = m * 64 + wm * 32 + (l & 31);
                int off = r * 32 + ((cbb ^ ((r >> 1) & 3)) << 3);
                ah[m] = *(const bf16x8*)&Ah[off];
                al[m] = *(const bf16x8*)&Al[off];
            }
            #pragma unroll
            for (int nf = 0; nf < 2; ++nf) {
                int tr = wn * 64 + nf * 32 + (l & 31);
                int off = tr * 32 + ((cbb ^ ((tr >> 1) & 3)) << 3);
                bf16x8 bh = *(const bf16x8*)&Bh[off];
                bf16x8 bl = *(const bf16x8*)&Bl[off];
                #pragma unroll
                for (int m = 0; m < NM; ++m) {
                    acc[m][nf] = __builtin_amdgcn_mfma_f32_32x32x16_bf16(ah[m], bh, acc[m][nf], 0, 0, 0);
                    acc[m][nf] = __builtin_amdgcn_mfma_f32_32x32x16_bf16(ah[m], bl, acc[m][nf], 0, 0, 0);
                    acc[m][nf] = __builtin_amdgcn_mfma_f32_32x32x16_bf16(al[m], bh, acc[m][nf], 0, 0, 0);
                }
            }
        }
    };

    stage(0, 0);
    __syncthreads();                       // vmcnt(0) drain -> buf0 ready
    for (int ks = 0; ks < 6; ++ks) {
        if (ks < 5) stage((ks + 1) & 1, (ks + 1) * 32);  // issue next tile
        compute(ks & 1);                                  // MFMA on current
        __syncthreads();                   // drains next tile's loads + reuse fence
    }

    float* Os[3] = {O0, O1, O2};
    #pragma unroll
    for (int m = 0; m < NM; ++m) {
        float* O = Os[m] + (size_t)blockIdx.z * Cn * Tn;
        #pragma unroll
        for (int nf = 0; nf < 2; ++nf) {
            int col = t0 + wn * 64 + nf * 32 + (l & 31);
            #pragma unroll
            for (int r = 0; r < 16; ++r) {
                int row = m0 + wm * 32 + (r & 3) + 8 * (r >> 2) + 4 * (l >> 5);
                O[(size_t)row * Tn + col] = acc[m][nf][r];
            }
        }
    }
}

// ---------------------------------------------------------------------------
// Kernel 4: bidirectional WKV + sigmoid(receptance); outputs split bf16 hi/lo.
// ---------------------------------------------------------------------------
__global__ __launch_bounds__(256) void wkv_kernel(const float* __restrict__ kg,
                                                  const float* __restrict__ vg,
                                                  const float* __restrict__ srlg,
                                                  const float* __restrict__ decay,
                                                  const float* __restrict__ boost,
                                                  u16* __restrict__ yhi,
                                                  u16* __restrict__ ylo) {
    const int row = blockIdx.x;       // b*C + d
    const int d = row % Cn;
    const float* kr = kg + (size_t)row * Tn;
    const float* vr = vg + (size_t)row * Tn;
    const float* sr = srlg + (size_t)row * Tn;
    u16* yh = yhi + (size_t)row * Tn;
    u16* yl = ylo + (size_t)row * Tn;

    const int tid = threadIdx.x;
    const int t0 = tid * 16;

    float kk[16], vv[16];
    #pragma unroll
    for (int j = 0; j < 16; j += 4) {
        *(float4*)&kk[j] = *(const float4*)&kr[t0 + j];
        *(float4*)&vv[j] = *(const float4*)&vr[t0 + j];
    }

    __shared__ float red[256];
    float lm = kk[0];
    #pragma unroll
    for (int j = 1; j < 16; ++j) lm = fmaxf(lm, kk[j]);
    red[tid] = lm;
    __syncthreads();
    for (int s = 128; s > 0; s >>= 1) {
        if (tid < s) red[tid] = fmaxf(red[tid], red[tid + s]);
        __syncthreads();
    }
    const float m = red[0];
    __syncthreads();

    const float ww = decay[d] * (1.0f / (float)Tn);
    const float u = boost[d] * (1.0f / (float)Tn);
    const float lam = expf(-ww);
    const float lam16 = expf(-16.0f * ww);

    float a[16];
    #pragma unroll
    for (int j = 0; j < 16; ++j) a[j] = expf(kk[j] - m);

    float SN = 0.f, SD = 0.f;
    #pragma unroll
    for (int j = 0; j < 16; ++j) { SN = fmaf(lam, SN, a[j] * vv[j]); SD = fmaf(lam, SD, a[j]); }
    float BN = 0.f, BD = 0.f;
    #pragma unroll
    for (int j = 15; j >= 0; --j) { BN = fmaf(lam, BN, a[j] * vv[j]); BD = fmaf(lam, BD, a[j]); }

    __shared__ float sN[2][256], sD[2][256];

    sN[0][tid] = SN; sD[0][tid] = SD;
    __syncthreads();
    int src = 0;
    float f = lam16;
    for (int o = 1; o < 256; o <<= 1) {
        float nN = sN[src][tid], nD = sD[src][tid];
        if (tid >= o) { nN = fmaf(f, sN[src][tid - o], nN); nD = fmaf(f, sD[src][tid - o], nD); }
        sN[src ^ 1][tid] = nN; sD[src ^ 1][tid] = nD;
        __syncthreads();
        src ^= 1; f = f * f;
    }
    const float CfN = (tid > 0) ? sN[src][tid - 1] : 0.f;
    const float CfD = (tid > 0) ? sD[src][tid - 1] : 0.f;
    __syncthreads();

    sN[0][tid] = BN; sD[0][tid] = BD;
    __syncthreads();
    src = 0; f = lam16;
    for (int o = 1; o < 256; o <<= 1) {
        float nN = sN[src][tid], nD = sD[src][tid];
        if (tid + o < 256) { nN = fmaf(f, sN[src][tid + o], nN); nD = fmaf(f, sD[src][tid + o], nD); }
        sN[src ^ 1][tid] = nN; sD[src ^ 1][tid] = nD;
        __syncthreads();
        src ^= 1; f = f * f;
    }
    const float CbN = (tid < 255) ? sN[src][tid + 1] : 0.f;
    const float CbD = (tid < 255) ? sD[src][tid + 1] : 0.f;

    float fN[16], fD[16];
    float cN = CfN, cD = CfD;
    #pragma unroll
    for (int j = 0; j < 16; ++j) {
        fN[j] = cN; fD[j] = cD;
        cN = fmaf(lam, cN, a[j] * vv[j]);
        cD = fmaf(lam, cD, a[j]);
    }

    float sl[16];
    #pragma unroll
    for (int j = 0; j < 16; j += 4) *(float4*)&sl[j] = *(const float4*)&sr[t0 + j];

    u16 oh[16], ol[16];
    float bN = CbN, bD = CbD;
    #pragma unroll
    for (int j = 15; j >= 0; --j) {
        const float es = expf(u + kk[j] - m);
        const float num = fN[j] + bN + es * vv[j];
        const float den = fD[j] + bD + es;
        const float y = num / den;
        const float sig = 1.0f / (1.0f + expf(-sl[j]));
        split_bf16(sig * y, oh[j], ol[j]);
        bN = fmaf(lam, bN, a[j] * vv[j]);
        bD = fmaf(lam, bD, a[j]);
    }

    u32 ph[8], pl[8];
    #pragma unroll
    for (int j = 0; j < 8; ++j) {
        ph[j] = (u32)oh[2 * j] | ((u32)oh[2 * j + 1] << 16);
        pl[j] = (u32)ol[2 * j] | ((u32)ol[2 * j + 1] << 16);
    }
    *(uint4*)&yh[t0]     = make_uint4(ph[0], ph[1], ph[2], ph[3]);
    *(uint4*)&yh[t0 + 8] = make_uint4(ph[4], ph[5], ph[6], ph[7]);
    *(uint4*)&yl[t0]     = make_uint4(pl[0], pl[1], pl[2], pl[3]);
    *(uint4*)&yl[t0 + 8] = make_uint4(pl[4], pl[5], pl[6], pl[7]);
}

// ---------------------------------------------------------------------------
extern "C" void kernel_launch(void* const* d_in, const int* in_sizes, int n_in,
                              void* d_out, int out_size, void* d_ws, size_t ws_size,
                              hipStream_t stream) {
    const float* x        = (const float*)d_in[0];
    const float* w_key    = (const float*)d_in[1];
    const float* w_value  = (const float*)d_in[2];
    const float* w_recept = (const float*)d_in[3];
    const float* w_out    = (const float*)d_in[4];
    const float* decay    = (const float*)d_in[5];
    const float* boost    = (const float*)d_in[6];
    const float* alpha    = (const float*)d_in[7];
    const float* dw1      = (const float*)d_in[8];
    const float* dw3      = (const float*)d_in[9];
    const float* dw5      = (const float*)d_in[10];

    const size_t S = (size_t)Bn * Cn * Tn;   // 6291456 elements
    u16* R0 = (u16*)d_ws;                    // 2S u16 each region
    u16* R1 = R0 + 2 * S;
    u16* R2 = R1 + 2 * S;
    u16* whp = R2 + 2 * S;                   // stacked weights hi (4*36864)
    u16* wlp = whp + 4 * 36864;

    u16* xs_hi = R0;        u16* xs_lo = R0 + S;      // omni out / transpose in
    u16* Xt_hi = R1;        u16* Xt_lo = R1 + S;      // transpose out / proj in
    float* kb  = (float*)R0;                          // proj out (xs dead)
    float* vb  = (float*)R2;
    float* srl = (float*)d_out;                       // scratch until final GEMM
    u16* y_hi  = R1;        u16* y_lo  = R1 + S;      // wkv out (Xt dead)
    u16* Yt_hi = R2;        u16* Yt_lo = R2 + S;      // y-transpose out (vb dead)
    float* out = (float*)d_out;

    wsplit_kernel<<<dim3(144, 4), 256, 0, stream>>>(w_key, w_value, w_recept, w_out, whp, wlp);

    omni_kernel<<<dim3(Bn * Cn), 256, 0, stream>>>(x, alpha, dw1, dw3, dw5, xs_hi, xs_lo);

    transpose_kernel<<<dim3(32, 6, 8), 256, 0, stream>>>(xs_hi, xs_lo, Xt_hi, Xt_lo);

    gemm_mfma<3><<<dim3(32, 3, 8), 256, 0, stream>>>(whp, wlp, Xt_hi, Xt_lo, kb, vb, srl, 0);

    wkv_kernel<<<dim3(Bn * Cn), 256, 0, stream>>>(kb, vb, srl, decay, boost, y_hi, y_lo);

    transpose_kernel<<<dim3(32, 6, 8), 256, 0, stream>>>(y_hi, y_lo, Yt_hi, Yt_lo);

    gemm_mfma<1><<<dim3(32, 3, 8), 256, 0, stream>>>(whp, wlp, Yt_hi, Yt_lo, out, nullptr, nullptr, 576);
}

// Round 6
// 119.162 us; speedup vs baseline: 1.9078x; 1.0304x over previous
//
#include <hip/hip_runtime.h>
#include <math.h>

#define Cn 192
#define Bn 8
#define Tn 4096
#define HW 64

typedef unsigned short u16;
typedef unsigned int u32;
typedef __attribute__((ext_vector_type(8))) __bf16 bf16x8;
typedef __attribute__((ext_vector_type(16))) float f32x16;

__device__ __forceinline__ void gload16(const void* g, void* l) {
    __builtin_amdgcn_global_load_lds(
        (const __attribute__((address_space(1))) void*)g,
        (__attribute__((address_space(3))) void*)l, 16, 0, 0);
}

__device__ __forceinline__ void split_bf16(float x, u16 &h, u16 &l) {
    u32 u = __float_as_uint(x);
    u32 uh = (u + 0x7FFFu + ((u >> 16) & 1u)) & 0xFFFF0000u;
    h = (u16)(uh >> 16);
    float r = x - __uint_as_float(uh);
    u32 ur = __float_as_uint(r);
    l = (u16)((ur + 0x7FFFu + ((ur >> 16) & 1u)) >> 16);
}

// ---------------------------------------------------------------------------
// Kernel 1: omni_shift (fused 25-tap depthwise conv) -> split bf16 hi/lo out.
// ---------------------------------------------------------------------------
__global__ __launch_bounds__(256) void omni_kernel(const float* __restrict__ x,
                                                   const float* __restrict__ alpha,
                                                   const float* __restrict__ dw1,
                                                   const float* __restrict__ dw3,
                                                   const float* __restrict__ dw5,
                                                   u16* __restrict__ xhi,
                                                   u16* __restrict__ xlo) {
    const int plane = blockIdx.x;          // b*C + c
    const int c = plane % Cn;
    const float* xin = x + (size_t)plane * Tn;
    u16* oh = xhi + (size_t)plane * Tn;
    u16* ol = xlo + (size_t)plane * Tn;

    __shared__ float tile[68 * 68];
    __shared__ float wk[25];

    const int tid = threadIdx.x;
    if (tid == 0) {
        const float a0 = alpha[0], a1 = alpha[1], a2 = alpha[2], a3 = alpha[3];
        #pragma unroll
        for (int j = 0; j < 25; ++j) wk[j] = a3 * dw5[c * 25 + j];
        #pragma unroll
        for (int dy = 0; dy < 3; ++dy)
            #pragma unroll
            for (int dx = 0; dx < 3; ++dx)
                wk[(dy + 1) * 5 + (dx + 1)] += a2 * dw3[c * 9 + dy * 3 + dx];
        wk[12] += a1 * dw1[c] + a0;
    }
    for (int i = tid; i < 68 * 68; i += 256) {
        int r = i / 68, cc = i - r * 68;
        int gy = r - 2, gx = cc - 2;
        float v = 0.f;
        if (gy >= 0 && gy < HW && gx >= 0 && gx < HW) v = xin[gy * HW + gx];
        tile[i] = v;
    }
    __syncthreads();

    const int py = tid >> 3;          // 0..31
    const int px0 = (tid & 7) << 3;   // 0,8,..,56

    #pragma unroll
    for (int half = 0; half < 2; ++half) {
        const int y = py + half * 32;
        float row[5][12];
        #pragma unroll
        for (int dy = 0; dy < 5; ++dy) {
            const float4* rp = (const float4*)&tile[(y + dy) * 68 + px0];
            float4 r0 = rp[0], r1 = rp[1], r2 = rp[2];
            row[dy][0] = r0.x; row[dy][1] = r0.y; row[dy][2]  = r0.z; row[dy][3]  = r0.w;
            row[dy][4] = r1.x; row[dy][5] = r1.y; row[dy][6]  = r1.z; row[dy][7]  = r1.w;
            row[dy][8] = r2.x; row[dy][9] = r2.y; row[dy][10] = r2.z; row[dy][11] = r2.w;
        }
        u32 ph[4], pl[4];
        #pragma unroll
        for (int jj = 0; jj < 8; ++jj) {
            float acc = 0.f;
            #pragma unroll
            for (int dy = 0; dy < 5; ++dy)
                #pragma unroll
                for (int dx = 0; dx < 5; ++dx)
                    acc = fmaf(row[dy][jj + dx], wk[dy * 5 + dx], acc);
            u16 h, l2;
            split_bf16(acc, h, l2);
            if (jj & 1) { ph[jj >> 1] |= ((u32)h) << 16; pl[jj >> 1] |= ((u32)l2) << 16; }
            else        { ph[jj >> 1] = h;               pl[jj >> 1] = l2; }
        }
        *(uint4*)&oh[y * 64 + px0] = make_uint4(ph[0], ph[1], ph[2], ph[3]);
        *(uint4*)&ol[y * 64 + px0] = make_uint4(pl[0], pl[1], pl[2], pl[3]);
    }
}

// ---------------------------------------------------------------------------
// Kernel 2: transpose [b][192][4096] -> [b][4096][192] for both hi and lo.
// Extra grid plane (blockIdx.z == 8) performs the weight hi/lo split (fused
// to save a dispatch).
// ---------------------------------------------------------------------------
__global__ __launch_bounds__(256) void transpose_kernel(const u16* __restrict__ ih,
                                                        const u16* __restrict__ il,
                                                        u16* __restrict__ oh,
                                                        u16* __restrict__ ol,
                                                        const float* __restrict__ Wk,
                                                        const float* __restrict__ Wv,
                                                        const float* __restrict__ Wr,
                                                        const float* __restrict__ Wo,
                                                        u16* __restrict__ wh,
                                                        u16* __restrict__ wl) {
    const int tid = threadIdx.x;
    if (blockIdx.z == 8) {
        // weight split: 4 * 36864 = 147456 elements over 192 blocks * 768
        const int base = (blockIdx.y * 32 + blockIdx.x) * 768;
        #pragma unroll
        for (int j = 0; j < 3; ++j) {
            int idx = base + j * 256 + tid;
            int mat = idx / 36864;
            int off = idx - mat * 36864;
            const float* src = (mat == 0) ? Wk : (mat == 1) ? Wv : (mat == 2) ? Wr : Wo;
            u16 h, l;
            split_bf16(src[off], h, l);
            wh[idx] = h;
            wl[idx] = l;
        }
        return;
    }

    __shared__ u32 T[2][128][21];
    const size_t ib = (size_t)blockIdx.z * Cn * Tn;
    const int c0 = blockIdx.y * 32, t0 = blockIdx.x * 128;

    {
        const int c2 = tid >> 4;            // 0..15 (c-pair)
        const int tc = (tid & 15) * 8;      // t offset 0..120
        const size_t ge = ib + (size_t)(c0 + 2 * c2) * Tn + t0 + tc;
        uint4 evh = *(const uint4*)&ih[ge];
        uint4 odh = *(const uint4*)&ih[ge + Tn];
        uint4 evl = *(const uint4*)&il[ge];
        uint4 odl = *(const uint4*)&il[ge + Tn];
        const u32 eh4[4] = {evh.x, evh.y, evh.z, evh.w};
        const u32 oh4[4] = {odh.x, odh.y, odh.z, odh.w};
        const u32 el4[4] = {evl.x, evl.y, evl.z, evl.w};
        const u32 ol4[4] = {odl.x, odl.y, odl.z, odl.w};
        #pragma unroll
        for (int q = 0; q < 4; ++q) {
            T[0][tc + 2 * q    ][c2] = (eh4[q] & 0xFFFFu) | (oh4[q] << 16);
            T[0][tc + 2 * q + 1][c2] = (eh4[q] >> 16) | (oh4[q] & 0xFFFF0000u);
            T[1][tc + 2 * q    ][c2] = (el4[q] & 0xFFFFu) | (ol4[q] << 16);
            T[1][tc + 2 * q + 1][c2] = (el4[q] >> 16) | (ol4[q] & 0xFFFF0000u);
        }
    }
    __syncthreads();
    {
        const int t = tid >> 1;
        const int hf = tid & 1;
        u32 wv[8][2];
        #pragma unroll
        for (int q = 0; q < 8; ++q) {
            wv[q][0] = T[0][t][hf * 8 + q];
            wv[q][1] = T[1][t][hf * 8 + q];
        }
        const size_t go = ib + (size_t)(t0 + t) * Cn + c0 + hf * 16;
        *(uint4*)&oh[go]     = make_uint4(wv[0][0], wv[1][0], wv[2][0], wv[3][0]);
        *(uint4*)&oh[go + 8] = make_uint4(wv[4][0], wv[5][0], wv[6][0], wv[7][0]);
        *(uint4*)&ol[go]     = make_uint4(wv[0][1], wv[1][1], wv[2][1], wv[3][1]);
        *(uint4*)&ol[go + 8] = make_uint4(wv[4][1], wv[5][1], wv[6][1], wv[7][1]);
    }
}

// ---------------------------------------------------------------------------
// Kernel 3: split-bf16 MFMA GEMM, global_load_lds staged.
// A (weights) SINGLE-buffered (re-staged per K-step, L2-hot), B (activations)
// double-buffered  ->  LDS 57.4 KB (NM=3) / 41 KB (NM=1)  ->  2-3 blocks/CU.
// Out_m[b][row][t] = sum_c W[wrow0 + m*192 + m0 + row][c] * Xt[b][t][c]
// ---------------------------------------------------------------------------
template<int NM>
__global__ __launch_bounds__(256) void gemm_mfma(const u16* __restrict__ wh,
                                                 const u16* __restrict__ wl,
                                                 const u16* __restrict__ Xh,
                                                 const u16* __restrict__ Xl,
                                                 float* __restrict__ O0,
                                                 float* __restrict__ O1,
                                                 float* __restrict__ O2,
                                                 int wrow0) {
    constexpr int ASZ = NM * 64 * 32;   // u16 per A array (hi or lo)
    constexpr int BSZ = 128 * 32;       // u16 per B array (hi or lo)
    __shared__ u16 A_[2 * ASZ];         // [hi | lo], single buffer
    __shared__ u16 B_[2][2 * BSZ];      // double buffer, [hi | lo]

    const int tid  = threadIdx.x;
    const int l    = tid & 63;
    const int wave = tid >> 6;
    const int wm   = wave >> 1, wn = wave & 1;
    const int m0   = blockIdx.y * 64;
    const int t0   = blockIdx.x * 128;
    const size_t xb = (size_t)blockIdx.z * Cn * Tn;

    f32x16 acc[NM][2];
    #pragma unroll
    for (int m = 0; m < NM; ++m)
        #pragma unroll
        for (int nf = 0; nf < 2; ++nf)
            #pragma unroll
            for (int r = 0; r < 16; ++r) acc[m][nf][r] = 0.f;

    auto stageA = [&](int k0) {
        #pragma unroll
        for (int i = 0; i < NM; ++i) {
            int idx = i * 256 + tid;
            int row = idx >> 2;
            int cb  = (idx & 3) ^ ((row >> 1) & 3);
            int grow = wrow0 + (row >> 6) * 192 + m0 + (row & 63);
            int dst = (i * 256 + wave * 64) * 8;
            gload16(wh + (size_t)grow * Cn + k0 + cb * 8, A_ + dst);
            gload16(wl + (size_t)grow * Cn + k0 + cb * 8, A_ + ASZ + dst);
        }
    };
    auto stageB = [&](int bf, int k0) {
        #pragma unroll
        for (int i = 0; i < 2; ++i) {
            int idx = i * 256 + tid;
            int tr  = idx >> 2;
            int cb  = (idx & 3) ^ ((tr >> 1) & 3);
            int dst = (i * 256 + wave * 64) * 8;
            gload16(Xh + xb + (size_t)(t0 + tr) * Cn + k0 + cb * 8, B_[bf] + dst);
            gload16(Xl + xb + (size_t)(t0 + tr) * Cn + k0 + cb * 8, B_[bf] + BSZ + dst);
        }
    };
    auto compute = [&](int bf) {
        const u16* Ah = A_;
        const u16* Al = A_ + ASZ;
        const u16* Bh = B_[bf];
        const u16* Bl = B_[bf] + BSZ;
        #pragma unroll
        for (int kh = 0; kh < 2; ++kh) {
            const int cbb = kh * 2 + (l >> 5);
            bf16x8 ah[NM], al[NM];
            #pragma unroll
            for (int m = 0; m < NM; ++m) {
                int r = m * 64 + wm * 32 + (l & 31);
                int off = r * 32 + ((cbb ^ ((r >> 1) & 3)) << 3);
                ah[m] = *(const bf16x8*)&Ah[off];
                al[m] = *(const bf16x8*)&Al[off];
            }
            #pragma unroll
            for (int nf = 0; nf < 2; ++nf) {
                int tr = wn * 64 + nf * 32 + (l & 31);
                int off = tr * 32 + ((cbb ^ ((tr >> 1) & 3)) << 3);
                bf16x8 bh = *(const bf16x8*)&Bh[off];
                bf16x8 bl = *(const bf16x8*)&Bl[off];
                #pragma unroll
                for (int m = 0; m < NM; ++m) {
                    acc[m][nf] = __builtin_amdgcn_mfma_f32_32x32x16_bf16(ah[m], bh, acc[m][nf], 0, 0, 0);
                    acc[m][nf] = __builtin_amdgcn_mfma_f32_32x32x16_bf16(ah[m], bl, acc[m][nf], 0, 0, 0);
                    acc[m][nf] = __builtin_amdgcn_mfma_f32_32x32x16_bf16(al[m], bh, acc[m][nf], 0, 0, 0);
                }
            }
        }
    };

    stageA(0);
    stageB(0, 0);
    __syncthreads();                       // buf0 + A(0) ready
    for (int ks = 0; ks < 6; ++ks) {
        if (ks < 5) stageB((ks + 1) & 1, (ks + 1) * 32);   // issue next B early
        compute(ks & 1);
        __syncthreads();                   // compute done; B(next) drained under compute
        if (ks < 5) {
            stageA((ks + 1) * 32);         // overwrite A (safe: compute done)
            __syncthreads();               // A(next) ready
        }
    }

    float* Os[3] = {O0, O1, O2};
    #pragma unroll
    for (int m = 0; m < NM; ++m) {
        float* O = Os[m] + (size_t)blockIdx.z * Cn * Tn;
        #pragma unroll
        for (int nf = 0; nf < 2; ++nf) {
            int col = t0 + wn * 64 + nf * 32 + (l & 31);
            #pragma unroll
            for (int r = 0; r < 16; ++r) {
                int row = m0 + wm * 32 + (r & 3) + 8 * (r >> 2) + 4 * (l >> 5);
                O[(size_t)row * Tn + col] = acc[m][nf][r];
            }
        }
    }
}

// ---------------------------------------------------------------------------
// Kernel 4: bidirectional WKV + sigmoid(receptance); outputs split bf16 hi/lo.
// ---------------------------------------------------------------------------
__global__ __launch_bounds__(256) void wkv_kernel(const float* __restrict__ kg,
                                                  const float* __restrict__ vg,
                                                  const float* __restrict__ srlg,
                                                  const float* __restrict__ decay,
                                                  const float* __restrict__ boost,
                                                  u16* __restrict__ yhi,
                                                  u16* __restrict__ ylo) {
    const int row = blockIdx.x;       // b*C + d
    const int d = row % Cn;
    const float* kr = kg + (size_t)row * Tn;
    const float* vr = vg + (size_t)row * Tn;
    const float* sr = srlg + (size_t)row * Tn;
    u16* yh = yhi + (size_t)row * Tn;
    u16* yl = ylo + (size_t)row * Tn;

    const int tid = threadIdx.x;
    const int t0 = tid * 16;

    float kk[16], vv[16];
    #pragma unroll
    for (int j = 0; j < 16; j += 4) {
        *(float4*)&kk[j] = *(const float4*)&kr[t0 + j];
        *(float4*)&vv[j] = *(const float4*)&vr[t0 + j];
    }

    __shared__ float red[256];
    float lm = kk[0];
    #pragma unroll
    for (int j = 1; j < 16; ++j) lm = fmaxf(lm, kk[j]);
    red[tid] = lm;
    __syncthreads();
    for (int s = 128; s > 0; s >>= 1) {
        if (tid < s) red[tid] = fmaxf(red[tid], red[tid + s]);
        __syncthreads();
    }
    const float m = red[0];
    __syncthreads();

    const float ww = decay[d] * (1.0f / (float)Tn);
    const float u = boost[d] * (1.0f / (float)Tn);
    const float lam = expf(-ww);
    const float lam16 = expf(-16.0f * ww);

    float a[16];
    #pragma unroll
    for (int j = 0; j < 16; ++j) a[j] = expf(kk[j] - m);

    float SN = 0.f, SD = 0.f;
    #pragma unroll
    for (int j = 0; j < 16; ++j) { SN = fmaf(lam, SN, a[j] * vv[j]); SD = fmaf(lam, SD, a[j]); }
    float BN = 0.f, BD = 0.f;
    #pragma unroll
    for (int j = 15; j >= 0; --j) { BN = fmaf(lam, BN, a[j] * vv[j]); BD = fmaf(lam, BD, a[j]); }

    __shared__ float sN[2][256], sD[2][256];

    sN[0][tid] = SN; sD[0][tid] = SD;
    __syncthreads();
    int src = 0;
    float f = lam16;
    for (int o = 1; o < 256; o <<= 1) {
        float nN = sN[src][tid], nD = sD[src][tid];
        if (tid >= o) { nN = fmaf(f, sN[src][tid - o], nN); nD = fmaf(f, sD[src][tid - o], nD); }
        sN[src ^ 1][tid] = nN; sD[src ^ 1][tid] = nD;
        __syncthreads();
        src ^= 1; f = f * f;
    }
    const float CfN = (tid > 0) ? sN[src][tid - 1] : 0.f;
    const float CfD = (tid > 0) ? sD[src][tid - 1] : 0.f;
    __syncthreads();

    sN[0][tid] = BN; sD[0][tid] = BD;
    __syncthreads();
    src = 0; f = lam16;
    for (int o = 1; o < 256; o <<= 1) {
        float nN = sN[src][tid], nD = sD[src][tid];
        if (tid + o < 256) { nN = fmaf(f, sN[src][tid + o], nN); nD = fmaf(f, sD[src][tid + o], nD); }
        sN[src ^ 1][tid] = nN; sD[src ^ 1][tid] = nD;
        __syncthreads();
        src ^= 1; f = f * f;
    }
    const float CbN = (tid < 255) ? sN[src][tid + 1] : 0.f;
    const float CbD = (tid < 255) ? sD[src][tid + 1] : 0.f;

    float fN[16], fD[16];
    float cN = CfN, cD = CfD;
    #pragma unroll
    for (int j = 0; j < 16; ++j) {
        fN[j] = cN; fD[j] = cD;
        cN = fmaf(lam, cN, a[j] * vv[j]);
        cD = fmaf(lam, cD, a[j]);
    }

    float sl[16];
    #pragma unroll
    for (int j = 0; j < 16; j += 4) *(float4*)&sl[j] = *(const float4*)&sr[t0 + j];

    u16 oh[16], ol[16];
    float bN = CbN, bD = CbD;
    #pragma unroll
    for (int j = 15; j >= 0; --j) {
        const float es = expf(u + kk[j] - m);
        const float num = fN[j] + bN + es * vv[j];
        const float den = fD[j] + bD + es;
        const float y = num / den;
        const float sig = 1.0f / (1.0f + expf(-sl[j]));
        split_bf16(sig * y, oh[j], ol[j]);
        bN = fmaf(lam, bN, a[j] * vv[j]);
        bD = fmaf(lam, bD, a[j]);
    }

    u32 ph[8], pl[8];
    #pragma unroll
    for (int j = 0; j < 8; ++j) {
        ph[j] = (u32)oh[2 * j] | ((u32)oh[2 * j + 1] << 16);
        pl[j] = (u32)ol[2 * j] | ((u32)ol[2 * j + 1] << 16);
    }
    *(uint4*)&yh[t0]     = make_uint4(ph[0], ph[1], ph[2], ph[3]);
    *(uint4*)&yh[t0 + 8] = make_uint4(ph[4], ph[5], ph[6], ph[7]);
    *(uint4*)&yl[t0]     = make_uint4(pl[0], pl[1], pl[2], pl[3]);
    *(uint4*)&yl[t0 + 8] = make_uint4(pl[4], pl[5], pl[6], pl[7]);
}

// ---------------------------------------------------------------------------
extern "C" void kernel_launch(void* const* d_in, const int* in_sizes, int n_in,
                              void* d_out, int out_size, void* d_ws, size_t ws_size,
                              hipStream_t stream) {
    const float* x        = (const float*)d_in[0];
    const float* w_key    = (const float*)d_in[1];
    const float* w_value  = (const float*)d_in[2];
    const float* w_recept = (const float*)d_in[3];
    const float* w_out    = (const float*)d_in[4];
    const float* decay    = (const float*)d_in[5];
    const float* boost    = (const float*)d_in[6];
    const float* alpha    = (const float*)d_in[7];
    const float* dw1      = (const float*)d_in[8];
    const float* dw3      = (const float*)d_in[9];
    const float* dw5      = (const float*)d_in[10];

    const size_t S = (size_t)Bn * Cn * Tn;   // 6291456 elements
    u16* R0 = (u16*)d_ws;                    // 2S u16 each region
    u16* R1 = R0 + 2 * S;
    u16* R2 = R1 + 2 * S;
    u16* whp = R2 + 2 * S;                   // stacked weights hi (4*36864)
    u16* wlp = whp + 4 * 36864;

    u16* xs_hi = R0;        u16* xs_lo = R0 + S;      // omni out / transpose in
    u16* Xt_hi = R1;        u16* Xt_lo = R1 + S;      // transpose out / proj in
    float* kb  = (float*)R0;                          // proj out (xs dead)
    float* vb  = (float*)R2;
    float* srl = (float*)d_out;                       // scratch until final GEMM
    u16* y_hi  = R1;        u16* y_lo  = R1 + S;      // wkv out (Xt dead)
    u16* Yt_hi = R2;        u16* Yt_lo = R2 + S;      // y-transpose out (vb dead)
    float* out = (float*)d_out;

    omni_kernel<<<dim3(Bn * Cn), 256, 0, stream>>>(x, alpha, dw1, dw3, dw5, xs_hi, xs_lo);

    // z-plane 8 also performs the weight hi/lo split
    transpose_kernel<<<dim3(32, 6, 9), 256, 0, stream>>>(xs_hi, xs_lo, Xt_hi, Xt_lo,
                                                         w_key, w_value, w_recept, w_out,
                                                         whp, wlp);

    gemm_mfma<3><<<dim3(32, 3, 8), 256, 0, stream>>>(whp, wlp, Xt_hi, Xt_lo, kb, vb, srl, 0);

    wkv_kernel<<<dim3(Bn * Cn), 256, 0, stream>>>(kb, vb, srl, decay, boost, y_hi, y_lo);

    transpose_kernel<<<dim3(32, 6, 8), 256, 0, stream>>>(y_hi, y_lo, Yt_hi, Yt_lo,
                                                         w_key, w_value, w_recept, w_out,
                                                         whp, wlp);

    gemm_mfma<1><<<dim3(32, 3, 8), 256, 0, stream>>>(whp, wlp, Yt_hi, Yt_lo, out, nullptr, nullptr, 576);
}